// Round 13
// baseline (1715.835 us; speedup 1.0000x reference)
//
#include <hip/hip_runtime.h>
#include <hip/hip_bf16.h>
#include <cmath>

#define SEQ 1024
#define EMBED 1280
#define HEADS 16
#define HD 80
#define HDP 96
#define MLP_DIM 5120
#define HIDDEN 3584
#define QKV3 3840
#define PATCH_DIMS 1176
#define PATCH_PAD 1184
#define DEPTH 8
#define MSEQ 256
#define MDIM 5120
#define KVSPLIT 4

typedef short short8 __attribute__((ext_vector_type(8)));
typedef short short4v __attribute__((ext_vector_type(4)));
typedef float f32x4 __attribute__((ext_vector_type(4)));

#define GLOAD16(g, l)                                                          \
  __builtin_amdgcn_global_load_lds(                                            \
      (const __attribute__((address_space(1))) void*)(g),                      \
      (__attribute__((address_space(3))) void*)(l), 16, 0, 0)

__device__ __forceinline__ float bf2f(unsigned short u) {
  union { unsigned int i; float f; } x;
  x.i = ((unsigned int)u) << 16;
  return x.f;
}
__device__ __forceinline__ unsigned short f2bf(float f) {
  union { float f; unsigned int i; } x;
  x.f = f;
  unsigned int r = x.i + 0x7fffu + ((x.i >> 16) & 1u);
  return (unsigned short)(r >> 16);
}

__device__ inline float waveReduceSum(float v) {
#pragma unroll
  for (int o = 32; o; o >>= 1) v += __shfl_xor(v, o);
  return v;
}

// ---------------- RoPE tables ----------------
__global__ void rope_tables_kernel(const int* gh_p, const int* gw_p,
                                   float* __restrict__ cosT, float* __restrict__ sinT) {
  int s = blockIdx.x;
  int j = threadIdx.x;
  if (j >= 40) return;
  int gh = *gh_p, gw = *gw_p;
  int f = s % (gh * gw);
  int d0 = f & 1;
  int b = (f >> 1) & 1;
  int rest = f >> 2;
  int W2 = gw >> 1;
  int c = rest % W2;
  int a = rest / W2;
  int hpos = a * 2 + b;
  int wpos = c * 2 + d0;
  int jp = j % 20;
  float inv = powf(10000.0f, -(2.0f * (float)jp) / 40.0f);
  float val = (float)(j < 20 ? hpos : wpos) * inv;
  cosT[s * 40 + j] = cosf(val);
  sinT[s * 40 + j] = sinf(val);
}

// ---------------- weight transpose+convert v2: wide reads/writes ----------------
__global__ __launch_bounds__(256) void transpose_w(
    const float* __restrict__ W, int ldW, long long wstep,
    unsigned short* __restrict__ Wt, long long tstep, int Ksrc, int Kpad) {
  __shared__ float t[32][132];
  W += (long long)blockIdx.z * wstep;
  Wt += (long long)blockIdx.z * tstep;
  int k0 = blockIdx.x << 7, n0 = blockIdx.y << 5;
#pragma unroll
  for (int i = 0; i < 4; ++i) {
    int flat = threadIdx.x + (i << 8);
    int r = flat >> 3, c4 = (flat & 7) << 2;
    float4 v = make_float4(0.f, 0.f, 0.f, 0.f);
    if (k0 + r < Ksrc) v = *(const float4*)&W[(long long)(k0 + r) * ldW + n0 + c4];
    t[c4][r] = v.x;
    t[c4 + 1][r] = v.y;
    t[c4 + 2][r] = v.z;
    t[c4 + 3][r] = v.w;
  }
  __syncthreads();
  int n = threadIdx.x >> 3, kb = (threadIdx.x & 7) << 2;
#pragma unroll
  for (int j = 0; j < 4; ++j) {
    int k = kb + (j << 5);
    if (k0 + k < Kpad) {
      short4v o;
      o[0] = (short)f2bf(t[n][k]);
      o[1] = (short)f2bf(t[n][k + 1]);
      o[2] = (short)f2bf(t[n][k + 2]);
      o[3] = (short)f2bf(t[n][k + 3]);
      *(short4v*)&Wt[(long long)(n0 + n) * Kpad + k0 + k] = o;
    }
  }
}

// ---------------- x convert ----------------
__global__ __launch_bounds__(256) void convert_x(const float* __restrict__ x,
                                                 unsigned short* __restrict__ xb) {
  int idx = blockIdx.x * 256 + threadIdx.x;
  if (idx >= SEQ * PATCH_PAD) return;
  int j = idx % PATCH_PAD, s = idx / PATCH_PAD;
  xb[idx] = (j < PATCH_DIMS) ? f2bf(x[(long long)s * PATCH_DIMS + j]) : 0;
}

// ---------------- split-K bf16 MFMA GEMM (128x128), XCD-swizzled ----------------
// mode 0: bf16 partial at part[bz][M][N]; mode 3: (s==1) bf16 out = swish(v+bias)
__global__ __launch_bounds__(256) void gemm_sk(
    const unsigned short* __restrict__ A, int lda,
    const unsigned short* __restrict__ Bt, int ldb,
    void* __restrict__ outp, const float* __restrict__ bias,
    int M, int N, int K, int chunk, int mode) {
  __shared__ short As[128 * 32];
  __shared__ short Bs[128 * 32];
  int nbx = gridDim.x, nby = gridDim.y, nbz = gridDim.z;
  int orig = blockIdx.x + nbx * (blockIdx.y + nby * blockIdx.z);
  int nwg = nbx * nby * nbz;
  int q = nwg >> 3, r = nwg & 7;
  int xcd = orig & 7, pos = orig >> 3;
  int lid = (xcd < r ? xcd * (q + 1) : r * (q + 1) + (xcd - r) * q) + pos;
  int bx = lid % nbx;
  int tt = lid / nbx;
  int by = tt % nby;
  int bz = tt / nby;

  int bm = by << 7, bn = bx << 7;
  int k0 = bz * chunk;
  int kend = min(K, k0 + chunk);
  int tid = threadIdx.x;
  int lane = tid & 63, wid = tid >> 6;
  int wr = wid >> 1, wc = wid & 1;
  f32x4 acc[4][4] = {};

  int arow = (wid << 4) + (lane >> 2);
  int kblk = (lane & 3) << 3;
  const unsigned short* ga = A + (long long)(bm + arow) * lda + k0 + kblk;
  const unsigned short* gb = Bt + (long long)(bn + arow) * ldb + k0 + kblk;
  short* la = &As[arow * 32 + kblk];
  short* lb = &Bs[arow * 32 + kblk];
  long long stepA = 64LL * lda, stepB = 64LL * ldb;

  int l15 = lane & 15, kb8 = (lane >> 4) << 3;
  int rowA = (wr << 6) + l15;
  int rowB = (wc << 6) + l15;

  for (int k = k0; k < kend; k += 32) {
    __syncthreads();
    GLOAD16(ga, la);
    GLOAD16(ga + stepA, la + 64 * 32);
    GLOAD16(gb, lb);
    GLOAD16(gb + stepB, lb + 64 * 32);
    ga += 32;
    gb += 32;
    __syncthreads();
    short8 af[4], bfr[4];
#pragma unroll
    for (int m = 0; m < 4; ++m)
      af[m] = *(const short8*)&As[(rowA + (m << 4)) * 32 + kb8];
#pragma unroll
    for (int n = 0; n < 4; ++n)
      bfr[n] = *(const short8*)&Bs[(rowB + (n << 4)) * 32 + kb8];
#pragma unroll
    for (int m = 0; m < 4; ++m)
#pragma unroll
      for (int n = 0; n < 4; ++n)
        acc[m][n] = __builtin_amdgcn_mfma_f32_16x16x32_bf16(af[m], bfr[n], acc[m][n], 0, 0, 0);
  }

  int lg = lane >> 4;
  unsigned short* Cp = (unsigned short*)outp + (long long)bz * M * N;
  unsigned short* Cb = (unsigned short*)outp;
#pragma unroll
  for (int m = 0; m < 4; ++m) {
    int row0 = bm + (wr << 6) + (m << 4) + (lg << 2);
#pragma unroll
    for (int n = 0; n < 4; ++n) {
      int col = bn + (wc << 6) + (n << 4) + l15;
      float bval = (mode == 3) ? bias[col] : 0.f;
#pragma unroll
      for (int r2 = 0; r2 < 4; ++r2) {
        int row = row0 + r2;
        float v = acc[m][n][r2];
        if (mode == 0) {
          Cp[(long long)row * N + col] = f2bf(v);
        } else {
          v += bval;
          Cb[(long long)row * N + col] = f2bf(v / (1.0f + __expf(-1.702f * v)));
        }
      }
    }
  }
}

// ---------------- split-K reduce (bf16 partials) + epilogue ----------------
// mode: 0 f32 (+bias if non-null) | 3 bf16 swish+bias | 4 bf16 gelu+bias
__global__ __launch_bounds__(256) void reduce_sk(
    const unsigned short* __restrict__ P, long long MN, int nsplit,
    const float* __restrict__ bias,
    void* __restrict__ out, int N, int ldout, int colbase, int mode) {
  long long i = ((long long)blockIdx.x * 256 + threadIdx.x) * 4;
  if (i >= MN) return;
  float v[4] = {0.f, 0.f, 0.f, 0.f};
  for (int s = 0; s < nsplit; ++s) {
    short4v p = *(const short4v*)&P[s * MN + i];
#pragma unroll
    for (int j = 0; j < 4; ++j) v[j] += bf2f((unsigned short)p[j]);
  }
  int row = (int)(i / N), col = (int)(i % N);
  if (bias) {
    float4 bv = *(const float4*)&bias[col];
    v[0] += bv.x; v[1] += bv.y; v[2] += bv.z; v[3] += bv.w;
  }
  long long oi = (long long)row * ldout + colbase + col;
  if (mode == 0) {
    *(float4*)&((float*)out)[oi] = make_float4(v[0], v[1], v[2], v[3]);
  } else if (mode == 3) {
    short4v o;
#pragma unroll
    for (int j = 0; j < 4; ++j)
      o[j] = (short)f2bf(v[j] / (1.0f + __expf(-1.702f * v[j])));
    *(short4v*)&((unsigned short*)out)[oi] = o;
  } else {
    short4v o;
#pragma unroll
    for (int j = 0; j < 4; ++j)
      o[j] = (short)f2bf(0.5f * v[j] * (1.0f + tanhf(0.79788456080286535588f *
                                                     (v[j] + 0.044715f * v[j] * v[j] * v[j]))));
    *(short4v*)&((unsigned short*)out)[oi] = o;
  }
}

// ---------------- split-K reduce (bf16) + residual + LayerNorm fusion ----------------
__global__ __launch_bounds__(320) void reduce_ln(
    const unsigned short* __restrict__ P, int nsplit,
    const float* __restrict__ bias, const float* __restrict__ res,
    const float* __restrict__ g, const float* __restrict__ b,
    float* __restrict__ hout, unsigned short* __restrict__ yout) {
  int r = blockIdx.x, tid = threadIdx.x;
  int c4 = tid << 2;
  const long long MN = (long long)SEQ * EMBED;
  const unsigned short* prow = P + (long long)r * EMBED;
  __shared__ float r0[5], r1[5];
  float4 v = make_float4(0.f, 0.f, 0.f, 0.f);
  if (bias) v = *(const float4*)&bias[c4];
  for (int z = 0; z < nsplit; ++z) {
    short4v p = *(const short4v*)&prow[(long long)z * MN + c4];
    v.x += bf2f((unsigned short)p[0]);
    v.y += bf2f((unsigned short)p[1]);
    v.z += bf2f((unsigned short)p[2]);
    v.w += bf2f((unsigned short)p[3]);
  }
  if (res) {
    float4 rv = *(const float4*)&res[(long long)r * EMBED + c4];
    v.x += rv.x; v.y += rv.y; v.z += rv.z; v.w += rv.w;
  }
  float s = v.x + v.y + v.z + v.w;
  float sq = v.x * v.x + v.y * v.y + v.z * v.z + v.w * v.w;
  s = waveReduceSum(s);
  sq = waveReduceSum(sq);
  int lane = tid & 63, wid = tid >> 6;
  if (!lane) { r0[wid] = s; r1[wid] = sq; }
  __syncthreads();
  s = r0[0] + r0[1] + r0[2] + r0[3] + r0[4];
  sq = r1[0] + r1[1] + r1[2] + r1[3] + r1[4];
  float mean = s * (1.0f / EMBED);
  float var = sq * (1.0f / EMBED) - mean * mean;
  float rstd = rsqrtf(var + 1e-6f);
  *(float4*)&hout[(long long)r * EMBED + c4] = v;
  float4 gv = *(const float4*)&g[c4];
  float4 bv = *(const float4*)&b[c4];
  short4v o;
  o[0] = (short)f2bf((v.x - mean) * rstd * gv.x + bv.x);
  o[1] = (short)f2bf((v.y - mean) * rstd * gv.y + bv.y);
  o[2] = (short)f2bf((v.z - mean) * rstd * gv.z + bv.z);
  o[3] = (short)f2bf((v.w - mean) * rstd * gv.w + bv.w);
  *(short4v*)&yout[(long long)r * EMBED + c4] = o;
}

// ---------------- fused qkv reduce: q/k rope (blocks 0..1023) + V pack (blocks 1024..1279) ----------------
__global__ __launch_bounds__(256) void reduce_qkvv(
    const unsigned short* __restrict__ P, int nsplit,
    const float* __restrict__ bias,
    const float* __restrict__ cosT, const float* __restrict__ sinT,
    unsigned short* __restrict__ qb, unsigned short* __restrict__ kb,
    unsigned short* __restrict__ vb, float qscale) {
  __shared__ unsigned short t[80][72];
  int b = blockIdx.x, tid = threadIdx.x;
  const long long MN = (long long)SEQ * QKV3;
  if (b < SEQ) {
    int s = b;
    const unsigned short* prow = P + (long long)s * QKV3;
    for (int idx = tid; idx < 640; idx += 256) {
      int hh = idx / 40, j = idx % 40;
      int cq = hh * 80 + j;
      float q0 = bias[cq], q1 = bias[cq + 40];
      float k0 = bias[1280 + cq], k1 = bias[1280 + cq + 40];
      for (int z = 0; z < nsplit; ++z) {
        const unsigned short* p = prow + (long long)z * MN;
        q0 += bf2f(p[cq]); q1 += bf2f(p[cq + 40]);
        k0 += bf2f(p[1280 + cq]); k1 += bf2f(p[1280 + cq + 40]);
      }
      float cs = cosT[s * 40 + j], sn = sinT[s * 40 + j];
      size_t o = ((size_t)hh * SEQ + s) * HDP;
      qb[o + j] = f2bf((q0 * cs - q1 * sn) * qscale);
      qb[o + j + 40] = f2bf((q1 * cs + q0 * sn) * qscale);
      kb[o + j] = f2bf(k0 * cs - k1 * sn);
      kb[o + j + 40] = f2bf(k1 * cs + k0 * sn);
    }
    {
      int hh = tid >> 4, p = 80 + (tid & 15);
      size_t o = ((size_t)hh * SEQ + s) * HDP + p;
      qb[o] = 0;
      kb[o] = 0;
    }
  } else {
    int bb = b - SEQ;
    int hh = bb >> 4, s0 = (bb & 15) << 6;
    int s = tid >> 2, c0 = (tid & 3) * 20;
    const unsigned short* prow =
        P + (long long)(s0 + s) * QKV3 + 2560 + hh * 80 + c0;
#pragma unroll
    for (int j = 0; j < 20; ++j) {
      float v = bias[2560 + hh * 80 + c0 + j];
      for (int z = 0; z < nsplit; ++z) v += bf2f(prow[(long long)z * MN + j]);
      t[c0 + j][s] = f2bf(v);
    }
    __syncthreads();
    unsigned short* dst = vb + (size_t)hh * 80 * SEQ + s0;
#pragma unroll
    for (int i = 0; i < 3; ++i) {
      int c = tid + (i << 8);
      if (c < 640) {
        int dr = c >> 3, col = (c & 7) << 3;
        *(short8*)&dst[(size_t)dr * SEQ + col] = *(const short8*)&t[dr][col];
      }
    }
  }
}

// ---------------- fused flash attention, KV-split x4, bf16 Opart ----------------
__global__ __launch_bounds__(256) void flash_attn_split(
    const unsigned short* __restrict__ qb,
    const unsigned short* __restrict__ kb,
    const unsigned short* __restrict__ vb,
    unsigned short* __restrict__ Opart, // [KVSPLIT][SEQ][EMBED] bf16
    float* __restrict__ mlbuf) {        // [z*2+{0:m,1:l}][HEADS][SEQ]
  __shared__ short Ks[64 * 104];
  __shared__ short Vs[80 * 72];
  __shared__ short Ps[4 * 16 * 72];
  int h = blockIdx.y, q0 = blockIdx.x << 6, z = blockIdx.z;
  int tid = threadIdx.x, lane = tid & 63, wid = tid >> 6;
  int l15 = lane & 15, lg = lane >> 4;
  int kb8 = lg << 3;

  short8 qf[3];
  {
    const unsigned short* qrow = qb + ((size_t)h * SEQ + q0 + (wid << 4) + l15) * HDP;
#pragma unroll
    for (int dc = 0; dc < 3; ++dc) qf[dc] = *(const short8*)&qrow[dc * 32 + kb8];
  }

  f32x4 o_acc[5] = {};
  float m_run = -1e30f, l_run = 0.f;
  short* myP = &Ps[(wid * 16 + l15) * 72];

  const int TPS = 16 / KVSPLIT;
  for (int t = z * TPS; t < z * TPS + TPS; ++t) {
    int kv0 = t << 6;
    __syncthreads();
    {
      const unsigned short* gk = kb + ((size_t)h * SEQ + kv0) * HDP;
#pragma unroll
      for (int i = 0; i < 3; ++i) {
        int c = tid + (i << 8);
        int row = c / 12, col = (c % 12) << 3;
        *(short8*)&Ks[row * 104 + col] = *(const short8*)&gk[row * HDP + col];
      }
      const unsigned short* gv = vb + (size_t)h * 80 * SEQ + kv0;
#pragma unroll
      for (int i = 0; i < 3; ++i) {
        int c = tid + (i << 8);
        if (c < 640) {
          int row = c >> 3, col = (c & 7) << 3;
          *(short8*)&Vs[row * 72 + col] = *(const short8*)&gv[(size_t)row * SEQ + col];
        }
      }
    }
    __syncthreads();

    f32x4 s[4] = {};
#pragma unroll
    for (int ks = 0; ks < 4; ++ks) {
#pragma unroll
      for (int dc = 0; dc < 3; ++dc) {
        short8 kf = *(const short8*)&Ks[(ks * 16 + l15) * 104 + dc * 32 + kb8];
        s[ks] = __builtin_amdgcn_mfma_f32_16x16x32_bf16(kf, qf[dc], s[ks], 0, 0, 0);
      }
    }

    float mloc = -1e30f;
#pragma unroll
    for (int ks = 0; ks < 4; ++ks)
#pragma unroll
      for (int r = 0; r < 4; ++r) mloc = fmaxf(mloc, s[ks][r]);
    mloc = fmaxf(mloc, __shfl_xor(mloc, 16));
    mloc = fmaxf(mloc, __shfl_xor(mloc, 32));
    float m_new = fmaxf(m_run, mloc);
    float alpha = __expf(m_run - m_new);
    float psum = 0.f;
#pragma unroll
    for (int ks = 0; ks < 4; ++ks) {
      short4v pk;
#pragma unroll
      for (int r = 0; r < 4; ++r) {
        float p = __expf(s[ks][r] - m_new);
        psum += p;
        pk[r] = (short)f2bf(p);
      }
      *(short4v*)&myP[ks * 16 + (lg << 2)] = pk;
    }
    psum += __shfl_xor(psum, 16);
    psum += __shfl_xor(psum, 32);
    l_run = l_run * alpha + psum;
    m_run = m_new;
#pragma unroll
    for (int dt = 0; dt < 5; ++dt)
#pragma unroll
      for (int r = 0; r < 4; ++r) o_acc[dt][r] *= alpha;

#pragma unroll
    for (int dt = 0; dt < 5; ++dt) {
#pragma unroll
      for (int kc = 0; kc < 2; ++kc) {
        short8 vf = *(const short8*)&Vs[(dt * 16 + l15) * 72 + kc * 32 + kb8];
        short8 pf = *(const short8*)&myP[kc * 32 + kb8];
        o_acc[dt] = __builtin_amdgcn_mfma_f32_16x16x32_bf16(vf, pf, o_acc[dt], 0, 0, 0);
      }
    }
  }

  int row = q0 + (wid << 4) + l15;
  unsigned short* orow = Opart + ((size_t)z * SEQ + row) * EMBED + h * HD;
#pragma unroll
  for (int dt = 0; dt < 5; ++dt) {
    short4v ov;
#pragma unroll
    for (int r = 0; r < 4; ++r) ov[r] = (short)f2bf(o_acc[dt][r]);
    *(short4v*)&orow[dt * 16 + (lg << 2)] = ov;
  }
  if (lg == 0) {
    mlbuf[((size_t)(z * 2 + 0) * HEADS + h) * SEQ + row] = m_run;
    mlbuf[((size_t)(z * 2 + 1) * HEADS + h) * SEQ + row] = l_run;
  }
}

// ---------------- combine the KV splits (bf16 Opart) ----------------
__global__ __launch_bounds__(320) void flash_combine(
    const unsigned short* __restrict__ Opart, const float* __restrict__ mlbuf,
    unsigned short* __restrict__ ob) {
  int s = blockIdx.x, tid = threadIdx.x;
  __shared__ float ws[KVSPLIT][16], ils[16];
  if (tid < 16) {
    float m = -1e30f;
    float mv[KVSPLIT], lv[KVSPLIT];
#pragma unroll
    for (int z = 0; z < KVSPLIT; ++z) {
      mv[z] = mlbuf[((size_t)(z * 2 + 0) * HEADS + tid) * SEQ + s];
      lv[z] = mlbuf[((size_t)(z * 2 + 1) * HEADS + tid) * SEQ + s];
      m = fmaxf(m, mv[z]);
    }
    float denom = 0.f;
#pragma unroll
    for (int z = 0; z < KVSPLIT; ++z) {
      float w = __expf(mv[z] - m);
      ws[z][tid] = w;
      denom += w * lv[z];
    }
    ils[tid] = 1.0f / denom;
  }
  __syncthreads();
  int c = tid << 2, hh = c / 80;
  float a0 = 0.f, a1 = 0.f, a2 = 0.f, a3 = 0.f;
#pragma unroll
  for (int z = 0; z < KVSPLIT; ++z) {
    short4v o = *(const short4v*)&Opart[((size_t)z * SEQ + s) * EMBED + c];
    float w = ws[z][hh];
    a0 += bf2f((unsigned short)o[0]) * w;
    a1 += bf2f((unsigned short)o[1]) * w;
    a2 += bf2f((unsigned short)o[2]) * w;
    a3 += bf2f((unsigned short)o[3]) * w;
  }
  float il = ils[hh];
  short4v o;
  o[0] = (short)f2bf(a0 * il);
  o[1] = (short)f2bf(a1 * il);
  o[2] = (short)f2bf(a2 * il);
  o[3] = (short)f2bf(a3 * il);
  *(short4v*)&ob[(size_t)s * EMBED + c] = o;
}

extern "C" void kernel_launch(void* const* d_in, const int* in_sizes, int n_in,
                              void* d_out, int out_size, void* d_ws, size_t ws_size,
                              hipStream_t stream) {
  const float* x = (const float*)d_in[0];
  const float* patch_w = (const float*)d_in[1];
  const float* ln1_g = (const float*)d_in[2];
  const float* ln1_b = (const float*)d_in[3];
  const float* qkv_w = (const float*)d_in[4];
  const float* qkv_b = (const float*)d_in[5];
  const float* proj_w = (const float*)d_in[6];
  const float* proj_b = (const float*)d_in[7];
  const float* ln2_g = (const float*)d_in[8];
  const float* ln2_b = (const float*)d_in[9];
  const float* fc1_w = (const float*)d_in[10];
  const float* fc1_b = (const float*)d_in[11];
  const float* fc2_w = (const float*)d_in[12];
  const float* fc2_b = (const float*)d_in[13];
  const float* mln_g = (const float*)d_in[14];
  const float* mln_b = (const float*)d_in[15];
  const float* mfc1_w = (const float*)d_in[16];
  const float* mfc1_b = (const float*)d_in[17];
  const float* mfc2_w = (const float*)d_in[18];
  const float* mfc2_b = (const float*)d_in[19];
  const int* grid_h = (const int*)d_in[21];
  const int* grid_w = (const int*)d_in[22];

  char* wsp = (char*)d_ws;
  char* ws0 = wsp;
  float* h = (float*)wsp;                       wsp += (size_t)SEQ * EMBED * 4;
  float* cosT = (float*)wsp;                    wsp += (size_t)SEQ * 40 * 4;
  float* sinT = (float*)wsp;                    wsp += (size_t)SEQ * 40 * 4;
  unsigned short* y = (unsigned short*)wsp;     wsp += (size_t)SEQ * EMBED * 2;
  unsigned short* ob = (unsigned short*)wsp;    wsp += (size_t)SEQ * EMBED * 2;
  unsigned short* m1b = (unsigned short*)wsp;   wsp += (size_t)MSEQ * MDIM * 2;
  unsigned short* qb = (unsigned short*)wsp;    wsp += (size_t)HEADS * SEQ * HDP * 2;
  unsigned short* kb = (unsigned short*)wsp;    wsp += (size_t)HEADS * SEQ * HDP * 2;
  unsigned short* vb = (unsigned short*)wsp;    wsp += (size_t)HEADS * HD * SEQ * 2;
  unsigned short* Opart = (unsigned short*)wsp; wsp += (size_t)KVSPLIT * SEQ * EMBED * 2;
  float* mlbuf = (float*)wsp;                   wsp += (size_t)2 * KVSPLIT * HEADS * SEQ * 4;
  unsigned short* u = (unsigned short*)wsp;     wsp += (size_t)SEQ * MLP_DIM * 2;
  unsigned short* xb = (unsigned short*)wsp;    wsp += (size_t)SEQ * PATCH_PAD * 2;
  unsigned short* wt = (unsigned short*)wsp;    wsp += (size_t)(MDIM / 2) * MDIM * 2;
  size_t fixed = (size_t)(wsp - ws0);

  const size_t E_QKV = (size_t)QKV3 * EMBED;
  const size_t E_PROJ = (size_t)EMBED * EMBED;
  const size_t E_FC1 = (size_t)MLP_DIM * EMBED;
  const size_t E_FC2 = (size_t)EMBED * MLP_DIM;
  const size_t E_PATCH = (size_t)EMBED * PATCH_PAD;
  const size_t E_M1 = (size_t)MDIM * MDIM;
  const size_t E_M2 = (size_t)HIDDEN * MDIM;
  size_t wregElems = DEPTH * (E_QKV + E_PROJ + E_FC1 + E_FC2) + E_PATCH + E_M1 + E_M2;
  size_t wregBytes = wregElems * 2;
  bool full = ws_size >= fixed + wregBytes + (size_t)90 * 1024 * 1024;

  unsigned short* wreg = (unsigned short*)wsp;
  unsigned short* Wq = wreg;
  unsigned short* Wp = Wq + DEPTH * E_QKV;
  unsigned short* Wf1 = Wp + DEPTH * E_PROJ;
  unsigned short* Wf2 = Wf1 + DEPTH * E_FC1;
  unsigned short* Wpa = Wf2 + DEPTH * E_FC2;
  unsigned short* Wm1 = Wpa + E_PATCH;
  unsigned short* Wm2 = Wm1 + E_M1;

  unsigned short* part =
      full ? (unsigned short*)(wsp + wregBytes) : (unsigned short*)wsp;
  size_t avail = ws_size - fixed - (full ? wregBytes : 0);

  auto splits_for = [&](long long MN, int want) {
    size_t one = (size_t)MN * 2;
    if (avail < one) return 1;
    long long cap = (long long)(avail / one);
    return (int)(want < cap ? want : cap);
  };
  auto chunk_for = [](int K, int s) { return ((K + s * 32 - 1) / (s * 32)) * 32; };

  const float scale = 1.0f / sqrtf(80.0f);
  dim3 blk(256);

  rope_tables_kernel<<<SEQ, 64, 0, stream>>>(grid_h, grid_w, cosT, sinT);
  convert_x<<<(SEQ * PATCH_PAD + 255) / 256, blk, 0, stream>>>(x, xb);

  if (full) {
    transpose_w<<<dim3((PATCH_PAD + 127) / 128, EMBED / 32, 1), blk, 0, stream>>>(
        patch_w, EMBED, 0, Wpa, 0, PATCH_DIMS, PATCH_PAD);
    transpose_w<<<dim3(EMBED / 128, QKV3 / 32, DEPTH), blk, 0, stream>>>(
        qkv_w, QKV3, (long long)EMBED * QKV3, Wq, (long long)E_QKV, EMBED, EMBED);
    transpose_w<<<dim3(EMBED / 128, EMBED / 32, DEPTH), blk, 0, stream>>>(
        proj_w, EMBED, (long long)EMBED * EMBED, Wp, (long long)E_PROJ, EMBED, EMBED);
    transpose_w<<<dim3(EMBED / 128, MLP_DIM / 32, DEPTH), blk, 0, stream>>>(
        fc1_w, MLP_DIM, (long long)EMBED * MLP_DIM, Wf1, (long long)E_FC1, EMBED, EMBED);
    transpose_w<<<dim3(MLP_DIM / 128, EMBED / 32, DEPTH), blk, 0, stream>>>(
        fc2_w, EMBED, (long long)MLP_DIM * EMBED, Wf2, (long long)E_FC2, MLP_DIM, MLP_DIM);
    transpose_w<<<dim3(MDIM / 128, MDIM / 32, 1), blk, 0, stream>>>(
        mfc1_w, MDIM, 0, Wm1, 0, MDIM, MDIM);
    transpose_w<<<dim3(MDIM / 128, HIDDEN / 32, 1), blk, 0, stream>>>(
        mfc2_w, HIDDEN, 0, Wm2, 0, MDIM, MDIM);
  }

  // ---- patch embed + LN1(layer0): split 8 (640 blocks) ----
  {
    const unsigned short* W = Wpa;
    if (!full) {
      transpose_w<<<dim3((PATCH_PAD + 127) / 128, EMBED / 32, 1), blk, 0, stream>>>(
          patch_w, EMBED, 0, wt, 0, PATCH_DIMS, PATCH_PAD);
      W = wt;
    }
    long long MN = (long long)SEQ * EMBED;
    int s = splits_for(MN, 8), ch = chunk_for(PATCH_PAD, s);
    gemm_sk<<<dim3(EMBED / 128, SEQ / 128, s), blk, 0, stream>>>(
        xb, PATCH_PAD, W, PATCH_PAD, part, nullptr, SEQ, EMBED, PATCH_PAD, ch, 0);
    reduce_ln<<<SEQ, 320, 0, stream>>>(part, s, nullptr, nullptr, ln1_g, ln1_b, h, y);
  }

  for (int l = 0; l < DEPTH; ++l) {
    // qkv: split 3 (720 blocks)
    int sq;
    {
      const unsigned short* W = Wq + (size_t)l * E_QKV;
      if (!full) {
        transpose_w<<<dim3(EMBED / 128, QKV3 / 32, 1), blk, 0, stream>>>(
            qkv_w + (long long)l * EMBED * QKV3, QKV3, 0, wt, 0, EMBED, EMBED);
        W = wt;
      }
      long long MN = (long long)SEQ * QKV3;
      sq = splits_for(MN, 3);
      int ch = chunk_for(EMBED, sq);
      gemm_sk<<<dim3(QKV3 / 128, SEQ / 128, sq), blk, 0, stream>>>(
          y, EMBED, W, EMBED, part, nullptr, SEQ, QKV3, EMBED, ch, 0);
      reduce_qkvv<<<SEQ + 16 * HEADS, blk, 0, stream>>>(
          part, sq, qkv_b + l * QKV3, cosT, sinT, qb, kb, vb, scale);
    }
    flash_attn_split<<<dim3(SEQ / 64, HEADS, KVSPLIT), blk, 0, stream>>>(
        qb, kb, vb, Opart, mlbuf);
    flash_combine<<<SEQ, 320, 0, stream>>>(Opart, mlbuf, ob);
    // proj: split 8 (640 blocks), reduce_ln (+res +LN2)
    {
      const unsigned short* W = Wp + (size_t)l * E_PROJ;
      if (!full) {
        transpose_w<<<dim3(EMBED / 128, EMBED / 32, 1), blk, 0, stream>>>(
            proj_w + (long long)l * EMBED * EMBED, EMBED, 0, wt, 0, EMBED, EMBED);
        W = wt;
      }
      long long MN = (long long)SEQ * EMBED;
      int s = splits_for(MN, 8), ch = chunk_for(EMBED, s);
      gemm_sk<<<dim3(EMBED / 128, SEQ / 128, s), blk, 0, stream>>>(
          ob, EMBED, W, EMBED, part, nullptr, SEQ, EMBED, EMBED, ch, 0);
      reduce_ln<<<SEQ, 320, 0, stream>>>(part, s, proj_b + l * EMBED, h,
                                         ln2_g + l * EMBED, ln2_b + l * EMBED, h, y);
    }
    // fc1: split 2 (640 blocks) + swish reduce -> u bf16
    {
      const unsigned short* W = Wf1 + (size_t)l * E_FC1;
      if (!full) {
        transpose_w<<<dim3(EMBED / 128, MLP_DIM / 32, 1), blk, 0, stream>>>(
            fc1_w + (long long)l * EMBED * MLP_DIM, MLP_DIM, 0, wt, 0, EMBED, EMBED);
        W = wt;
      }
      long long MN = (long long)SEQ * MLP_DIM;
      int s = splits_for(MN, 2), ch = chunk_for(EMBED, s);
      gemm_sk<<<dim3(MLP_DIM / 128, SEQ / 128, s), blk, 0, stream>>>(
          y, EMBED, W, EMBED, part, nullptr, SEQ, MLP_DIM, EMBED, ch, 0);
      reduce_sk<<<(MN / 4 + 255) / 256, blk, 0, stream>>>(
          part, MN, s, fc1_b + l * MLP_DIM, u, MLP_DIM, MLP_DIM, 0, 3);
    }
    // fc2: split 10 (800 blocks), reduce_ln (+res +next-LN)
    {
      const unsigned short* W = Wf2 + (size_t)l * E_FC2;
      if (!full) {
        transpose_w<<<dim3(MLP_DIM / 128, EMBED / 32, 1), blk, 0, stream>>>(
            fc2_w + (long long)l * MLP_DIM * EMBED, EMBED, 0, wt, 0, MLP_DIM, MLP_DIM);
        W = wt;
      }
      long long MN = (long long)SEQ * EMBED;
      int s = splits_for(MN, 10), ch = chunk_for(MLP_DIM, s);
      gemm_sk<<<dim3(EMBED / 128, SEQ / 128, s), blk, 0, stream>>>(
          u, MLP_DIM, W, MLP_DIM, part, nullptr, SEQ, EMBED, MLP_DIM, ch, 0);
      const float* ng = (l < DEPTH - 1) ? ln1_g + (l + 1) * EMBED : mln_g;
      const float* nb = (l < DEPTH - 1) ? ln1_b + (l + 1) * EMBED : mln_b;
      reduce_ln<<<SEQ, 320, 0, stream>>>(part, s, fc2_b + l * EMBED, h, ng, nb, h, y);
    }
  }

  // ---- merger ----
  if (full) {
    {
      long long MN = (long long)MSEQ * MDIM;
      int s = splits_for(MN, 12), ch = chunk_for(MDIM, s);
      gemm_sk<<<dim3(MDIM / 128, MSEQ / 128, s), blk, 0, stream>>>(
          y, MDIM, Wm1, MDIM, part, nullptr, MSEQ, MDIM, MDIM, ch, 0);
      reduce_sk<<<(MN / 4 + 255) / 256, blk, 0, stream>>>(
          part, MN, s, mfc1_b, m1b, MDIM, MDIM, 0, 4);
    }
    {
      long long MN = (long long)MSEQ * HIDDEN;
      int s = splits_for(MN, 12), ch = chunk_for(MDIM, s);
      gemm_sk<<<dim3(HIDDEN / 128, MSEQ / 128, s), blk, 0, stream>>>(
          m1b, MDIM, Wm2, MDIM, part, nullptr, MSEQ, HIDDEN, MDIM, ch, 0);
      reduce_sk<<<(MN / 4 + 255) / 256, blk, 0, stream>>>(
          part, MN, s, mfc2_b, (float*)d_out, HIDDEN, HIDDEN, 0, 0);
    }
  } else {
    for (int hh = 0; hh < 2; ++hh) {
      transpose_w<<<dim3(MDIM / 128, 2560 / 32, 1), blk, 0, stream>>>(
          mfc1_w + hh * 2560, MDIM, 0, wt, 0, MDIM, MDIM);
      long long MN = (long long)MSEQ * 2560;
      int s = splits_for(MN, 8), ch = chunk_for(MDIM, s);
      gemm_sk<<<dim3(2560 / 128, MSEQ / 128, s), blk, 0, stream>>>(
          y, MDIM, wt, MDIM, part, nullptr, MSEQ, 2560, MDIM, ch, 0);
      reduce_sk<<<(MN / 4 + 255) / 256, blk, 0, stream>>>(
          part, MN, s, mfc1_b + hh * 2560, m1b, 2560, MDIM, hh * 2560, 4);
    }
    for (int hh = 0; hh < 2; ++hh) {
      transpose_w<<<dim3(MDIM / 128, 1792 / 32, 1), blk, 0, stream>>>(
          mfc2_w + hh * 1792, HIDDEN, 0, wt, 0, MDIM, MDIM);
      long long MN = (long long)MSEQ * 1792;
      int s = splits_for(MN, 8), ch = chunk_for(MDIM, s);
      gemm_sk<<<dim3(1792 / 128, MSEQ / 128, s), blk, 0, stream>>>(
          m1b, MDIM, wt, MDIM, part, nullptr, MSEQ, 1792, MDIM, ch, 0);
      reduce_sk<<<(MN / 4 + 255) / 256, blk, 0, stream>>>(
          part, MN, s, mfc2_b + hh * 1792, (float*)d_out, 1792, HIDDEN, hh * 1792, 0);
    }
  }
}

// Round 14
// 1634.576 us; speedup vs baseline: 1.0497x; 1.0497x over previous
//
#include <hip/hip_runtime.h>
#include <hip/hip_bf16.h>
#include <cmath>

#define SEQ 1024
#define EMBED 1280
#define HEADS 16
#define HD 80
#define HDP 96
#define MLP_DIM 5120
#define HIDDEN 3584
#define QKV3 3840
#define PATCH_DIMS 1176
#define PATCH_PAD 1184
#define DEPTH 8
#define MSEQ 256
#define MDIM 5120
#define KVSPLIT 4

typedef short short8 __attribute__((ext_vector_type(8)));
typedef short short4v __attribute__((ext_vector_type(4)));
typedef float f32x4 __attribute__((ext_vector_type(4)));

#define GLOAD16(g, l)                                                          \
  __builtin_amdgcn_global_load_lds(                                            \
      (const __attribute__((address_space(1))) void*)(g),                      \
      (__attribute__((address_space(3))) void*)(l), 16, 0, 0)

__device__ __forceinline__ float bf2f(unsigned short u) {
  union { unsigned int i; float f; } x;
  x.i = ((unsigned int)u) << 16;
  return x.f;
}
__device__ __forceinline__ unsigned short f2bf(float f) {
  union { float f; unsigned int i; } x;
  x.f = f;
  unsigned int r = x.i + 0x7fffu + ((x.i >> 16) & 1u);
  return (unsigned short)(r >> 16);
}

__device__ inline float waveReduceSum(float v) {
#pragma unroll
  for (int o = 32; o; o >>= 1) v += __shfl_xor(v, o);
  return v;
}

// ---------------- RoPE tables ----------------
__global__ void rope_tables_kernel(const int* gh_p, const int* gw_p,
                                   float* __restrict__ cosT, float* __restrict__ sinT) {
  int s = blockIdx.x;
  int j = threadIdx.x;
  if (j >= 40) return;
  int gh = *gh_p, gw = *gw_p;
  int f = s % (gh * gw);
  int d0 = f & 1;
  int b = (f >> 1) & 1;
  int rest = f >> 2;
  int W2 = gw >> 1;
  int c = rest % W2;
  int a = rest / W2;
  int hpos = a * 2 + b;
  int wpos = c * 2 + d0;
  int jp = j % 20;
  float inv = powf(10000.0f, -(2.0f * (float)jp) / 40.0f);
  float val = (float)(j < 20 ? hpos : wpos) * inv;
  cosT[s * 40 + j] = cosf(val);
  sinT[s * 40 + j] = sinf(val);
}

// ---------------- weight transpose+convert v2: wide reads/writes ----------------
__global__ __launch_bounds__(256) void transpose_w(
    const float* __restrict__ W, int ldW, long long wstep,
    unsigned short* __restrict__ Wt, long long tstep, int Ksrc, int Kpad) {
  __shared__ float t[32][132];
  W += (long long)blockIdx.z * wstep;
  Wt += (long long)blockIdx.z * tstep;
  int k0 = blockIdx.x << 7, n0 = blockIdx.y << 5;
#pragma unroll
  for (int i = 0; i < 4; ++i) {
    int flat = threadIdx.x + (i << 8);
    int r = flat >> 3, c4 = (flat & 7) << 2;
    float4 v = make_float4(0.f, 0.f, 0.f, 0.f);
    if (k0 + r < Ksrc) v = *(const float4*)&W[(long long)(k0 + r) * ldW + n0 + c4];
    t[c4][r] = v.x;
    t[c4 + 1][r] = v.y;
    t[c4 + 2][r] = v.z;
    t[c4 + 3][r] = v.w;
  }
  __syncthreads();
  int n = threadIdx.x >> 3, kb = (threadIdx.x & 7) << 2;
#pragma unroll
  for (int j = 0; j < 4; ++j) {
    int k = kb + (j << 5);
    if (k0 + k < Kpad) {
      short4v o;
      o[0] = (short)f2bf(t[n][k]);
      o[1] = (short)f2bf(t[n][k + 1]);
      o[2] = (short)f2bf(t[n][k + 2]);
      o[3] = (short)f2bf(t[n][k + 3]);
      *(short4v*)&Wt[(long long)(n0 + n) * Kpad + k0 + k] = o;
    }
  }
}

// ---------------- x convert ----------------
__global__ __launch_bounds__(256) void convert_x(const float* __restrict__ x,
                                                 unsigned short* __restrict__ xb) {
  int idx = blockIdx.x * 256 + threadIdx.x;
  if (idx >= SEQ * PATCH_PAD) return;
  int j = idx % PATCH_PAD, s = idx / PATCH_PAD;
  xb[idx] = (j < PATCH_DIMS) ? f2bf(x[(long long)s * PATCH_DIMS + j]) : 0;
}

// ---------------- split-K bf16 MFMA GEMM (128x128), XCD-swizzled ----------------
// mode 0: bf16 partial at part[bz][M][N]; mode 3: (s==1) bf16 out = swish(v+bias)
__global__ __launch_bounds__(256) void gemm_sk(
    const unsigned short* __restrict__ A, int lda,
    const unsigned short* __restrict__ Bt, int ldb,
    void* __restrict__ outp, const float* __restrict__ bias,
    int M, int N, int K, int chunk, int mode) {
  __shared__ short As[128 * 32];
  __shared__ short Bs[128 * 32];
  int nbx = gridDim.x, nby = gridDim.y, nbz = gridDim.z;
  int orig = blockIdx.x + nbx * (blockIdx.y + nby * blockIdx.z);
  int nwg = nbx * nby * nbz;
  int q = nwg >> 3, r = nwg & 7;
  int xcd = orig & 7, pos = orig >> 3;
  int lid = (xcd < r ? xcd * (q + 1) : r * (q + 1) + (xcd - r) * q) + pos;
  int bx = lid % nbx;
  int tt = lid / nbx;
  int by = tt % nby;
  int bz = tt / nby;

  int bm = by << 7, bn = bx << 7;
  int k0 = bz * chunk;
  int kend = min(K, k0 + chunk);
  int tid = threadIdx.x;
  int lane = tid & 63, wid = tid >> 6;
  int wr = wid >> 1, wc = wid & 1;
  f32x4 acc[4][4] = {};

  int arow = (wid << 4) + (lane >> 2);
  int kblk = (lane & 3) << 3;
  const unsigned short* ga = A + (long long)(bm + arow) * lda + k0 + kblk;
  const unsigned short* gb = Bt + (long long)(bn + arow) * ldb + k0 + kblk;
  short* la = &As[arow * 32 + kblk];
  short* lb = &Bs[arow * 32 + kblk];
  long long stepA = 64LL * lda, stepB = 64LL * ldb;

  int l15 = lane & 15, kb8 = (lane >> 4) << 3;
  int rowA = (wr << 6) + l15;
  int rowB = (wc << 6) + l15;

  for (int k = k0; k < kend; k += 32) {
    __syncthreads();
    GLOAD16(ga, la);
    GLOAD16(ga + stepA, la + 64 * 32);
    GLOAD16(gb, lb);
    GLOAD16(gb + stepB, lb + 64 * 32);
    ga += 32;
    gb += 32;
    __syncthreads();
    short8 af[4], bfr[4];
#pragma unroll
    for (int m = 0; m < 4; ++m)
      af[m] = *(const short8*)&As[(rowA + (m << 4)) * 32 + kb8];
#pragma unroll
    for (int n = 0; n < 4; ++n)
      bfr[n] = *(const short8*)&Bs[(rowB + (n << 4)) * 32 + kb8];
#pragma unroll
    for (int m = 0; m < 4; ++m)
#pragma unroll
      for (int n = 0; n < 4; ++n)
        acc[m][n] = __builtin_amdgcn_mfma_f32_16x16x32_bf16(af[m], bfr[n], acc[m][n], 0, 0, 0);
  }

  int lg = lane >> 4;
  unsigned short* Cp = (unsigned short*)outp + (long long)bz * M * N;
  unsigned short* Cb = (unsigned short*)outp;
#pragma unroll
  for (int m = 0; m < 4; ++m) {
    int row0 = bm + (wr << 6) + (m << 4) + (lg << 2);
#pragma unroll
    for (int n = 0; n < 4; ++n) {
      int col = bn + (wc << 6) + (n << 4) + l15;
      float bval = (mode == 3) ? bias[col] : 0.f;
#pragma unroll
      for (int r2 = 0; r2 < 4; ++r2) {
        int row = row0 + r2;
        float v = acc[m][n][r2];
        if (mode == 0) {
          Cp[(long long)row * N + col] = f2bf(v);
        } else {
          v += bval;
          Cb[(long long)row * N + col] = f2bf(v / (1.0f + __expf(-1.702f * v)));
        }
      }
    }
  }
}

// ---------------- split-K reduce (bf16 partials) + epilogue ----------------
// mode: 0 f32 (+bias if non-null) | 3 bf16 swish+bias | 4 bf16 gelu+bias
__global__ __launch_bounds__(256) void reduce_sk(
    const unsigned short* __restrict__ P, long long MN, int nsplit,
    const float* __restrict__ bias,
    void* __restrict__ out, int N, int ldout, int colbase, int mode) {
  long long i = ((long long)blockIdx.x * 256 + threadIdx.x) * 4;
  if (i >= MN) return;
  float v[4] = {0.f, 0.f, 0.f, 0.f};
  for (int s = 0; s < nsplit; ++s) {
    short4v p = *(const short4v*)&P[s * MN + i];
#pragma unroll
    for (int j = 0; j < 4; ++j) v[j] += bf2f((unsigned short)p[j]);
  }
  int row = (int)(i / N), col = (int)(i % N);
  if (bias) {
    float4 bv = *(const float4*)&bias[col];
    v[0] += bv.x; v[1] += bv.y; v[2] += bv.z; v[3] += bv.w;
  }
  long long oi = (long long)row * ldout + colbase + col;
  if (mode == 0) {
    *(float4*)&((float*)out)[oi] = make_float4(v[0], v[1], v[2], v[3]);
  } else if (mode == 3) {
    short4v o;
#pragma unroll
    for (int j = 0; j < 4; ++j)
      o[j] = (short)f2bf(v[j] / (1.0f + __expf(-1.702f * v[j])));
    *(short4v*)&((unsigned short*)out)[oi] = o;
  } else {
    short4v o;
#pragma unroll
    for (int j = 0; j < 4; ++j)
      o[j] = (short)f2bf(0.5f * v[j] * (1.0f + tanhf(0.79788456080286535588f *
                                                     (v[j] + 0.044715f * v[j] * v[j] * v[j]))));
    *(short4v*)&((unsigned short*)out)[oi] = o;
  }
}

// ---------------- split-K reduce (bf16) + residual + LayerNorm fusion ----------------
__global__ __launch_bounds__(320) void reduce_ln(
    const unsigned short* __restrict__ P, int nsplit,
    const float* __restrict__ bias, const float* __restrict__ res,
    const float* __restrict__ g, const float* __restrict__ b,
    float* __restrict__ hout, unsigned short* __restrict__ yout) {
  int r = blockIdx.x, tid = threadIdx.x;
  int c4 = tid << 2;
  const long long MN = (long long)SEQ * EMBED;
  const unsigned short* prow = P + (long long)r * EMBED;
  __shared__ float r0[5], r1[5];
  float4 v = make_float4(0.f, 0.f, 0.f, 0.f);
  if (bias) v = *(const float4*)&bias[c4];
  for (int z = 0; z < nsplit; ++z) {
    short4v p = *(const short4v*)&prow[(long long)z * MN + c4];
    v.x += bf2f((unsigned short)p[0]);
    v.y += bf2f((unsigned short)p[1]);
    v.z += bf2f((unsigned short)p[2]);
    v.w += bf2f((unsigned short)p[3]);
  }
  if (res) {
    float4 rv = *(const float4*)&res[(long long)r * EMBED + c4];
    v.x += rv.x; v.y += rv.y; v.z += rv.z; v.w += rv.w;
  }
  float s = v.x + v.y + v.z + v.w;
  float sq = v.x * v.x + v.y * v.y + v.z * v.z + v.w * v.w;
  s = waveReduceSum(s);
  sq = waveReduceSum(sq);
  int lane = tid & 63, wid = tid >> 6;
  if (!lane) { r0[wid] = s; r1[wid] = sq; }
  __syncthreads();
  s = r0[0] + r0[1] + r0[2] + r0[3] + r0[4];
  sq = r1[0] + r1[1] + r1[2] + r1[3] + r1[4];
  float mean = s * (1.0f / EMBED);
  float var = sq * (1.0f / EMBED) - mean * mean;
  float rstd = rsqrtf(var + 1e-6f);
  *(float4*)&hout[(long long)r * EMBED + c4] = v;
  float4 gv = *(const float4*)&g[c4];
  float4 bv = *(const float4*)&b[c4];
  short4v o;
  o[0] = (short)f2bf((v.x - mean) * rstd * gv.x + bv.x);
  o[1] = (short)f2bf((v.y - mean) * rstd * gv.y + bv.y);
  o[2] = (short)f2bf((v.z - mean) * rstd * gv.z + bv.z);
  o[3] = (short)f2bf((v.w - mean) * rstd * gv.w + bv.w);
  *(short4v*)&yout[(long long)r * EMBED + c4] = o;
}

// ---------------- fused qkv reduce: q/k rope (blocks 0..1023) + V pack (blocks 1024..1279) ----------------
__global__ __launch_bounds__(256) void reduce_qkvv(
    const unsigned short* __restrict__ P, int nsplit,
    const float* __restrict__ bias,
    const float* __restrict__ cosT, const float* __restrict__ sinT,
    unsigned short* __restrict__ qb, unsigned short* __restrict__ kb,
    unsigned short* __restrict__ vb, float qscale) {
  __shared__ unsigned short t[80][72];
  int b = blockIdx.x, tid = threadIdx.x;
  const long long MN = (long long)SEQ * QKV3;
  if (b < SEQ) {
    int s = b;
    const unsigned short* prow = P + (long long)s * QKV3;
    for (int idx = tid; idx < 640; idx += 256) {
      int hh = idx / 40, j = idx % 40;
      int cq = hh * 80 + j;
      float q0 = bias[cq], q1 = bias[cq + 40];
      float k0 = bias[1280 + cq], k1 = bias[1280 + cq + 40];
      for (int z = 0; z < nsplit; ++z) {
        const unsigned short* p = prow + (long long)z * MN;
        q0 += bf2f(p[cq]); q1 += bf2f(p[cq + 40]);
        k0 += bf2f(p[1280 + cq]); k1 += bf2f(p[1280 + cq + 40]);
      }
      float cs = cosT[s * 40 + j], sn = sinT[s * 40 + j];
      size_t o = ((size_t)hh * SEQ + s) * HDP;
      qb[o + j] = f2bf((q0 * cs - q1 * sn) * qscale);
      qb[o + j + 40] = f2bf((q1 * cs + q0 * sn) * qscale);
      kb[o + j] = f2bf(k0 * cs - k1 * sn);
      kb[o + j + 40] = f2bf(k1 * cs + k0 * sn);
    }
    {
      int hh = tid >> 4, p = 80 + (tid & 15);
      size_t o = ((size_t)hh * SEQ + s) * HDP + p;
      qb[o] = 0;
      kb[o] = 0;
    }
  } else {
    int bb = b - SEQ;
    int hh = bb >> 4, s0 = (bb & 15) << 6;
    int s = tid >> 2, c0 = (tid & 3) * 20;
    const unsigned short* prow =
        P + (long long)(s0 + s) * QKV3 + 2560 + hh * 80 + c0;
#pragma unroll
    for (int j = 0; j < 20; ++j) {
      float v = bias[2560 + hh * 80 + c0 + j];
      for (int z = 0; z < nsplit; ++z) v += bf2f(prow[(long long)z * MN + j]);
      t[c0 + j][s] = f2bf(v);
    }
    __syncthreads();
    unsigned short* dst = vb + (size_t)hh * 80 * SEQ + s0;
#pragma unroll
    for (int i = 0; i < 3; ++i) {
      int c = tid + (i << 8);
      if (c < 640) {
        int dr = c >> 3, col = (c & 7) << 3;
        *(short8*)&dst[(size_t)dr * SEQ + col] = *(const short8*)&t[dr][col];
      }
    }
  }
}

// ---------------- fused flash attention, KV-split x4, bf16 Opart ----------------
__global__ __launch_bounds__(256) void flash_attn_split(
    const unsigned short* __restrict__ qb,
    const unsigned short* __restrict__ kb,
    const unsigned short* __restrict__ vb,
    unsigned short* __restrict__ Opart, // [KVSPLIT][SEQ][EMBED] bf16
    float* __restrict__ mlbuf) {        // [z*2+{0:m,1:l}][HEADS][SEQ]
  __shared__ short Ks[64 * 104];
  __shared__ short Vs[80 * 72];
  __shared__ short Ps[4 * 16 * 72];
  int h = blockIdx.y, q0 = blockIdx.x << 6, z = blockIdx.z;
  int tid = threadIdx.x, lane = tid & 63, wid = tid >> 6;
  int l15 = lane & 15, lg = lane >> 4;
  int kb8 = lg << 3;

  short8 qf[3];
  {
    const unsigned short* qrow = qb + ((size_t)h * SEQ + q0 + (wid << 4) + l15) * HDP;
#pragma unroll
    for (int dc = 0; dc < 3; ++dc) qf[dc] = *(const short8*)&qrow[dc * 32 + kb8];
  }

  f32x4 o_acc[5] = {};
  float m_run = -1e30f, l_run = 0.f;
  short* myP = &Ps[(wid * 16 + l15) * 72];

  const int TPS = 16 / KVSPLIT;
  for (int t = z * TPS; t < z * TPS + TPS; ++t) {
    int kv0 = t << 6;
    __syncthreads();
    {
      const unsigned short* gk = kb + ((size_t)h * SEQ + kv0) * HDP;
#pragma unroll
      for (int i = 0; i < 3; ++i) {
        int c = tid + (i << 8);
        int row = c / 12, col = (c % 12) << 3;
        *(short8*)&Ks[row * 104 + col] = *(const short8*)&gk[row * HDP + col];
      }
      const unsigned short* gv = vb + (size_t)h * 80 * SEQ + kv0;
#pragma unroll
      for (int i = 0; i < 3; ++i) {
        int c = tid + (i << 8);
        if (c < 640) {
          int row = c >> 3, col = (c & 7) << 3;
          *(short8*)&Vs[row * 72 + col] = *(const short8*)&gv[(size_t)row * SEQ + col];
        }
      }
    }
    __syncthreads();

    f32x4 s[4] = {};
#pragma unroll
    for (int ks = 0; ks < 4; ++ks) {
#pragma unroll
      for (int dc = 0; dc < 3; ++dc) {
        short8 kf = *(const short8*)&Ks[(ks * 16 + l15) * 104 + dc * 32 + kb8];
        s[ks] = __builtin_amdgcn_mfma_f32_16x16x32_bf16(kf, qf[dc], s[ks], 0, 0, 0);
      }
    }

    float mloc = -1e30f;
#pragma unroll
    for (int ks = 0; ks < 4; ++ks)
#pragma unroll
      for (int r = 0; r < 4; ++r) mloc = fmaxf(mloc, s[ks][r]);
    mloc = fmaxf(mloc, __shfl_xor(mloc, 16));
    mloc = fmaxf(mloc, __shfl_xor(mloc, 32));
    float m_new = fmaxf(m_run, mloc);
    float alpha = __expf(m_run - m_new);
    float psum = 0.f;
#pragma unroll
    for (int ks = 0; ks < 4; ++ks) {
      short4v pk;
#pragma unroll
      for (int r = 0; r < 4; ++r) {
        float p = __expf(s[ks][r] - m_new);
        psum += p;
        pk[r] = (short)f2bf(p);
      }
      *(short4v*)&myP[ks * 16 + (lg << 2)] = pk;
    }
    psum += __shfl_xor(psum, 16);
    psum += __shfl_xor(psum, 32);
    l_run = l_run * alpha + psum;
    m_run = m_new;
#pragma unroll
    for (int dt = 0; dt < 5; ++dt)
#pragma unroll
      for (int r = 0; r < 4; ++r) o_acc[dt][r] *= alpha;

#pragma unroll
    for (int dt = 0; dt < 5; ++dt) {
#pragma unroll
      for (int kc = 0; kc < 2; ++kc) {
        short8 vf = *(const short8*)&Vs[(dt * 16 + l15) * 72 + kc * 32 + kb8];
        short8 pf = *(const short8*)&myP[kc * 32 + kb8];
        o_acc[dt] = __builtin_amdgcn_mfma_f32_16x16x32_bf16(vf, pf, o_acc[dt], 0, 0, 0);
      }
    }
  }

  int row = q0 + (wid << 4) + l15;
  unsigned short* orow = Opart + ((size_t)z * SEQ + row) * EMBED + h * HD;
#pragma unroll
  for (int dt = 0; dt < 5; ++dt) {
    short4v ov;
#pragma unroll
    for (int r = 0; r < 4; ++r) ov[r] = (short)f2bf(o_acc[dt][r]);
    *(short4v*)&orow[dt * 16 + (lg << 2)] = ov;
  }
  if (lg == 0) {
    mlbuf[((size_t)(z * 2 + 0) * HEADS + h) * SEQ + row] = m_run;
    mlbuf[((size_t)(z * 2 + 1) * HEADS + h) * SEQ + row] = l_run;
  }
}

// ---------------- combine the KV splits (bf16 Opart) ----------------
__global__ __launch_bounds__(320) void flash_combine(
    const unsigned short* __restrict__ Opart, const float* __restrict__ mlbuf,
    unsigned short* __restrict__ ob) {
  int s = blockIdx.x, tid = threadIdx.x;
  __shared__ float ws[KVSPLIT][16], ils[16];
  if (tid < 16) {
    float m = -1e30f;
    float mv[KVSPLIT], lv[KVSPLIT];
#pragma unroll
    for (int z = 0; z < KVSPLIT; ++z) {
      mv[z] = mlbuf[((size_t)(z * 2 + 0) * HEADS + tid) * SEQ + s];
      lv[z] = mlbuf[((size_t)(z * 2 + 1) * HEADS + tid) * SEQ + s];
      m = fmaxf(m, mv[z]);
    }
    float denom = 0.f;
#pragma unroll
    for (int z = 0; z < KVSPLIT; ++z) {
      float w = __expf(mv[z] - m);
      ws[z][tid] = w;
      denom += w * lv[z];
    }
    ils[tid] = 1.0f / denom;
  }
  __syncthreads();
  int c = tid << 2, hh = c / 80;
  float a0 = 0.f, a1 = 0.f, a2 = 0.f, a3 = 0.f;
#pragma unroll
  for (int z = 0; z < KVSPLIT; ++z) {
    short4v o = *(const short4v*)&Opart[((size_t)z * SEQ + s) * EMBED + c];
    float w = ws[z][hh];
    a0 += bf2f((unsigned short)o[0]) * w;
    a1 += bf2f((unsigned short)o[1]) * w;
    a2 += bf2f((unsigned short)o[2]) * w;
    a3 += bf2f((unsigned short)o[3]) * w;
  }
  float il = ils[hh];
  short4v o;
  o[0] = (short)f2bf(a0 * il);
  o[1] = (short)f2bf(a1 * il);
  o[2] = (short)f2bf(a2 * il);
  o[3] = (short)f2bf(a3 * il);
  *(short4v*)&ob[(size_t)s * EMBED + c] = o;
}

extern "C" void kernel_launch(void* const* d_in, const int* in_sizes, int n_in,
                              void* d_out, int out_size, void* d_ws, size_t ws_size,
                              hipStream_t stream) {
  const float* x = (const float*)d_in[0];
  const float* patch_w = (const float*)d_in[1];
  const float* ln1_g = (const float*)d_in[2];
  const float* ln1_b = (const float*)d_in[3];
  const float* qkv_w = (const float*)d_in[4];
  const float* qkv_b = (const float*)d_in[5];
  const float* proj_w = (const float*)d_in[6];
  const float* proj_b = (const float*)d_in[7];
  const float* ln2_g = (const float*)d_in[8];
  const float* ln2_b = (const float*)d_in[9];
  const float* fc1_w = (const float*)d_in[10];
  const float* fc1_b = (const float*)d_in[11];
  const float* fc2_w = (const float*)d_in[12];
  const float* fc2_b = (const float*)d_in[13];
  const float* mln_g = (const float*)d_in[14];
  const float* mln_b = (const float*)d_in[15];
  const float* mfc1_w = (const float*)d_in[16];
  const float* mfc1_b = (const float*)d_in[17];
  const float* mfc2_w = (const float*)d_in[18];
  const float* mfc2_b = (const float*)d_in[19];
  const int* grid_h = (const int*)d_in[21];
  const int* grid_w = (const int*)d_in[22];

  char* wsp = (char*)d_ws;
  char* ws0 = wsp;
  float* h = (float*)wsp;                       wsp += (size_t)SEQ * EMBED * 4;
  float* cosT = (float*)wsp;                    wsp += (size_t)SEQ * 40 * 4;
  float* sinT = (float*)wsp;                    wsp += (size_t)SEQ * 40 * 4;
  unsigned short* y = (unsigned short*)wsp;     wsp += (size_t)SEQ * EMBED * 2;
  unsigned short* ob = (unsigned short*)wsp;    wsp += (size_t)SEQ * EMBED * 2;
  unsigned short* m1b = (unsigned short*)wsp;   wsp += (size_t)MSEQ * MDIM * 2;
  unsigned short* qb = (unsigned short*)wsp;    wsp += (size_t)HEADS * SEQ * HDP * 2;
  unsigned short* kb = (unsigned short*)wsp;    wsp += (size_t)HEADS * SEQ * HDP * 2;
  unsigned short* vb = (unsigned short*)wsp;    wsp += (size_t)HEADS * HD * SEQ * 2;
  unsigned short* Opart = (unsigned short*)wsp; wsp += (size_t)KVSPLIT * SEQ * EMBED * 2;
  float* mlbuf = (float*)wsp;                   wsp += (size_t)2 * KVSPLIT * HEADS * SEQ * 4;
  unsigned short* u = (unsigned short*)wsp;     wsp += (size_t)SEQ * MLP_DIM * 2;
  unsigned short* xb = (unsigned short*)wsp;    wsp += (size_t)SEQ * PATCH_PAD * 2;
  unsigned short* wt = (unsigned short*)wsp;    wsp += (size_t)(MDIM / 2) * MDIM * 2;
  size_t fixed = (size_t)(wsp - ws0);

  const size_t E_QKV = (size_t)QKV3 * EMBED;
  const size_t E_PROJ = (size_t)EMBED * EMBED;
  const size_t E_FC1 = (size_t)MLP_DIM * EMBED;
  const size_t E_FC2 = (size_t)EMBED * MLP_DIM;
  const size_t E_PATCH = (size_t)EMBED * PATCH_PAD;
  const size_t E_M1 = (size_t)MDIM * MDIM;
  const size_t E_M2 = (size_t)HIDDEN * MDIM;
  size_t wregElems = DEPTH * (E_QKV + E_PROJ + E_FC1 + E_FC2) + E_PATCH + E_M1 + E_M2;
  size_t wregBytes = wregElems * 2;
  bool full = ws_size >= fixed + wregBytes + (size_t)90 * 1024 * 1024;

  unsigned short* wreg = (unsigned short*)wsp;
  unsigned short* Wq = wreg;
  unsigned short* Wp = Wq + DEPTH * E_QKV;
  unsigned short* Wf1 = Wp + DEPTH * E_PROJ;
  unsigned short* Wf2 = Wf1 + DEPTH * E_FC1;
  unsigned short* Wpa = Wf2 + DEPTH * E_FC2;
  unsigned short* Wm1 = Wpa + E_PATCH;
  unsigned short* Wm2 = Wm1 + E_M1;

  unsigned short* part =
      full ? (unsigned short*)(wsp + wregBytes) : (unsigned short*)wsp;
  size_t avail = ws_size - fixed - (full ? wregBytes : 0);

  auto splits_for = [&](long long MN, int want) {
    size_t one = (size_t)MN * 2;
    if (avail < one) return 1;
    long long cap = (long long)(avail / one);
    return (int)(want < cap ? want : cap);
  };
  auto chunk_for = [](int K, int s) { return ((K + s * 32 - 1) / (s * 32)) * 32; };

  const float scale = 1.0f / sqrtf(80.0f);
  dim3 blk(256);

  rope_tables_kernel<<<SEQ, 64, 0, stream>>>(grid_h, grid_w, cosT, sinT);
  convert_x<<<(SEQ * PATCH_PAD + 255) / 256, blk, 0, stream>>>(x, xb);

  if (full) {
    transpose_w<<<dim3((PATCH_PAD + 127) / 128, EMBED / 32, 1), blk, 0, stream>>>(
        patch_w, EMBED, 0, Wpa, 0, PATCH_DIMS, PATCH_PAD);
    transpose_w<<<dim3(EMBED / 128, QKV3 / 32, DEPTH), blk, 0, stream>>>(
        qkv_w, QKV3, (long long)EMBED * QKV3, Wq, (long long)E_QKV, EMBED, EMBED);
    transpose_w<<<dim3(EMBED / 128, EMBED / 32, DEPTH), blk, 0, stream>>>(
        proj_w, EMBED, (long long)EMBED * EMBED, Wp, (long long)E_PROJ, EMBED, EMBED);
    transpose_w<<<dim3(EMBED / 128, MLP_DIM / 32, DEPTH), blk, 0, stream>>>(
        fc1_w, MLP_DIM, (long long)EMBED * MLP_DIM, Wf1, (long long)E_FC1, EMBED, EMBED);
    transpose_w<<<dim3(MLP_DIM / 128, EMBED / 32, DEPTH), blk, 0, stream>>>(
        fc2_w, EMBED, (long long)MLP_DIM * EMBED, Wf2, (long long)E_FC2, MLP_DIM, MLP_DIM);
    transpose_w<<<dim3(MDIM / 128, MDIM / 32, 1), blk, 0, stream>>>(
        mfc1_w, MDIM, 0, Wm1, 0, MDIM, MDIM);
    transpose_w<<<dim3(MDIM / 128, HIDDEN / 32, 1), blk, 0, stream>>>(
        mfc2_w, HIDDEN, 0, Wm2, 0, MDIM, MDIM);
  }

  // ---- patch embed + LN1(layer0): split 6 (480 blocks) ----
  {
    const unsigned short* W = Wpa;
    if (!full) {
      transpose_w<<<dim3((PATCH_PAD + 127) / 128, EMBED / 32, 1), blk, 0, stream>>>(
          patch_w, EMBED, 0, wt, 0, PATCH_DIMS, PATCH_PAD);
      W = wt;
    }
    long long MN = (long long)SEQ * EMBED;
    int s = splits_for(MN, 6), ch = chunk_for(PATCH_PAD, s);
    gemm_sk<<<dim3(EMBED / 128, SEQ / 128, s), blk, 0, stream>>>(
        xb, PATCH_PAD, W, PATCH_PAD, part, nullptr, SEQ, EMBED, PATCH_PAD, ch, 0);
    reduce_ln<<<SEQ, 320, 0, stream>>>(part, s, nullptr, nullptr, ln1_g, ln1_b, h, y);
  }

  for (int l = 0; l < DEPTH; ++l) {
    // qkv: split 2 (480 blocks)
    int sq;
    {
      const unsigned short* W = Wq + (size_t)l * E_QKV;
      if (!full) {
        transpose_w<<<dim3(EMBED / 128, QKV3 / 32, 1), blk, 0, stream>>>(
            qkv_w + (long long)l * EMBED * QKV3, QKV3, 0, wt, 0, EMBED, EMBED);
        W = wt;
      }
      long long MN = (long long)SEQ * QKV3;
      sq = splits_for(MN, 2);
      int ch = chunk_for(EMBED, sq);
      gemm_sk<<<dim3(QKV3 / 128, SEQ / 128, sq), blk, 0, stream>>>(
          y, EMBED, W, EMBED, part, nullptr, SEQ, QKV3, EMBED, ch, 0);
      reduce_qkvv<<<SEQ + 16 * HEADS, blk, 0, stream>>>(
          part, sq, qkv_b + l * QKV3, cosT, sinT, qb, kb, vb, scale);
    }
    flash_attn_split<<<dim3(SEQ / 64, HEADS, KVSPLIT), blk, 0, stream>>>(
        qb, kb, vb, Opart, mlbuf);
    flash_combine<<<SEQ, 320, 0, stream>>>(Opart, mlbuf, ob);
    // proj: split 6 (480 blocks), reduce_ln (+res +LN2)
    {
      const unsigned short* W = Wp + (size_t)l * E_PROJ;
      if (!full) {
        transpose_w<<<dim3(EMBED / 128, EMBED / 32, 1), blk, 0, stream>>>(
            proj_w + (long long)l * EMBED * EMBED, EMBED, 0, wt, 0, EMBED, EMBED);
        W = wt;
      }
      long long MN = (long long)SEQ * EMBED;
      int s = splits_for(MN, 6), ch = chunk_for(EMBED, s);
      gemm_sk<<<dim3(EMBED / 128, SEQ / 128, s), blk, 0, stream>>>(
          ob, EMBED, W, EMBED, part, nullptr, SEQ, EMBED, EMBED, ch, 0);
      reduce_ln<<<SEQ, 320, 0, stream>>>(part, s, proj_b + l * EMBED, h,
                                         ln2_g + l * EMBED, ln2_b + l * EMBED, h, y);
    }
    // fc1: split 2 (640 blocks) + swish reduce -> u bf16
    {
      const unsigned short* W = Wf1 + (size_t)l * E_FC1;
      if (!full) {
        transpose_w<<<dim3(EMBED / 128, MLP_DIM / 32, 1), blk, 0, stream>>>(
            fc1_w + (long long)l * EMBED * MLP_DIM, MLP_DIM, 0, wt, 0, EMBED, EMBED);
        W = wt;
      }
      long long MN = (long long)SEQ * MLP_DIM;
      int s = splits_for(MN, 2), ch = chunk_for(EMBED, s);
      gemm_sk<<<dim3(MLP_DIM / 128, SEQ / 128, s), blk, 0, stream>>>(
          y, EMBED, W, EMBED, part, nullptr, SEQ, MLP_DIM, EMBED, ch, 0);
      reduce_sk<<<(MN / 4 + 255) / 256, blk, 0, stream>>>(
          part, MN, s, fc1_b + l * MLP_DIM, u, MLP_DIM, MLP_DIM, 0, 3);
    }
    // fc2: split 8 (640 blocks), reduce_ln (+res +next-LN)
    {
      const unsigned short* W = Wf2 + (size_t)l * E_FC2;
      if (!full) {
        transpose_w<<<dim3(MLP_DIM / 128, EMBED / 32, 1), blk, 0, stream>>>(
            fc2_w + (long long)l * MLP_DIM * EMBED, EMBED, 0, wt, 0, MLP_DIM, MLP_DIM);
        W = wt;
      }
      long long MN = (long long)SEQ * EMBED;
      int s = splits_for(MN, 8), ch = chunk_for(MLP_DIM, s);
      gemm_sk<<<dim3(EMBED / 128, SEQ / 128, s), blk, 0, stream>>>(
          u, MLP_DIM, W, MLP_DIM, part, nullptr, SEQ, EMBED, MLP_DIM, ch, 0);
      const float* ng = (l < DEPTH - 1) ? ln1_g + (l + 1) * EMBED : mln_g;
      const float* nb = (l < DEPTH - 1) ? ln1_b + (l + 1) * EMBED : mln_b;
      reduce_ln<<<SEQ, 320, 0, stream>>>(part, s, fc2_b + l * EMBED, h, ng, nb, h, y);
    }
  }

  // ---- merger ----
  if (full) {
    {
      long long MN = (long long)MSEQ * MDIM;
      int s = splits_for(MN, 12), ch = chunk_for(MDIM, s);
      gemm_sk<<<dim3(MDIM / 128, MSEQ / 128, s), blk, 0, stream>>>(
          y, MDIM, Wm1, MDIM, part, nullptr, MSEQ, MDIM, MDIM, ch, 0);
      reduce_sk<<<(MN / 4 + 255) / 256, blk, 0, stream>>>(
          part, MN, s, mfc1_b, m1b, MDIM, MDIM, 0, 4);
    }
    {
      long long MN = (long long)MSEQ * HIDDEN;
      int s = splits_for(MN, 12), ch = chunk_for(MDIM, s);
      gemm_sk<<<dim3(HIDDEN / 128, MSEQ / 128, s), blk, 0, stream>>>(
          m1b, MDIM, Wm2, MDIM, part, nullptr, MSEQ, HIDDEN, MDIM, ch, 0);
      reduce_sk<<<(MN / 4 + 255) / 256, blk, 0, stream>>>(
          part, MN, s, mfc2_b, (float*)d_out, HIDDEN, HIDDEN, 0, 0);
    }
  } else {
    for (int hh = 0; hh < 2; ++hh) {
      transpose_w<<<dim3(MDIM / 128, 2560 / 32, 1), blk, 0, stream>>>(
          mfc1_w + hh * 2560, MDIM, 0, wt, 0, MDIM, MDIM);
      long long MN = (long long)MSEQ * 2560;
      int s = splits_for(MN, 8), ch = chunk_for(MDIM, s);
      gemm_sk<<<dim3(2560 / 128, MSEQ / 128, s), blk, 0, stream>>>(
          y, MDIM, wt, MDIM, part, nullptr, MSEQ, 2560, MDIM, ch, 0);
      reduce_sk<<<(MN / 4 + 255) / 256, blk, 0, stream>>>(
          part, MN, s, mfc1_b + hh * 2560, m1b, 2560, MDIM, hh * 2560, 4);
    }
    for (int hh = 0; hh < 2; ++hh) {
      transpose_w<<<dim3(MDIM / 128, 1792 / 32, 1), blk, 0, stream>>>(
          mfc2_w + hh * 1792, HIDDEN, 0, wt, 0, MDIM, MDIM);
      long long MN = (long long)MSEQ * 1792;
      int s = splits_for(MN, 8), ch = chunk_for(MDIM, s);
      gemm_sk<<<dim3(1792 / 128, MSEQ / 128, s), blk, 0, stream>>>(
          m1b, MDIM, wt, MDIM, part, nullptr, MSEQ, 1792, MDIM, ch, 0);
      reduce_sk<<<(MN / 4 + 255) / 256, blk, 0, stream>>>(
          part, MN, s, mfc2_b + hh * 1792, (float*)d_out, 1792, HIDDEN, hh * 1792, 0);
    }
  }
}

// Round 15
// 1628.819 us; speedup vs baseline: 1.0534x; 1.0035x over previous
//
#include <hip/hip_runtime.h>
#include <hip/hip_bf16.h>
#include <cmath>

#define SEQ 1024
#define EMBED 1280
#define HEADS 16
#define HD 80
#define HDP 96
#define MLP_DIM 5120
#define HIDDEN 3584
#define QKV3 3840
#define PATCH_DIMS 1176
#define PATCH_PAD 1184
#define DEPTH 8
#define MSEQ 256
#define MDIM 5120
#define KVSPLIT 4

typedef short short8 __attribute__((ext_vector_type(8)));
typedef short short4v __attribute__((ext_vector_type(4)));
typedef float f32x4 __attribute__((ext_vector_type(4)));

#define GLOAD16(g, l)                                                          \
  __builtin_amdgcn_global_load_lds(                                            \
      (const __attribute__((address_space(1))) void*)(g),                      \
      (__attribute__((address_space(3))) void*)(l), 16, 0, 0)

__device__ __forceinline__ float bf2f(unsigned short u) {
  union { unsigned int i; float f; } x;
  x.i = ((unsigned int)u) << 16;
  return x.f;
}
__device__ __forceinline__ unsigned short f2bf(float f) {
  union { float f; unsigned int i; } x;
  x.f = f;
  unsigned int r = x.i + 0x7fffu + ((x.i >> 16) & 1u);
  return (unsigned short)(r >> 16);
}

__device__ inline float waveReduceSum(float v) {
#pragma unroll
  for (int o = 32; o; o >>= 1) v += __shfl_xor(v, o);
  return v;
}

// ---------------- RoPE tables ----------------
__global__ void rope_tables_kernel(const int* gh_p, const int* gw_p,
                                   float* __restrict__ cosT, float* __restrict__ sinT) {
  int s = blockIdx.x;
  int j = threadIdx.x;
  if (j >= 40) return;
  int gh = *gh_p, gw = *gw_p;
  int f = s % (gh * gw);
  int d0 = f & 1;
  int b = (f >> 1) & 1;
  int rest = f >> 2;
  int W2 = gw >> 1;
  int c = rest % W2;
  int a = rest / W2;
  int hpos = a * 2 + b;
  int wpos = c * 2 + d0;
  int jp = j % 20;
  float inv = powf(10000.0f, -(2.0f * (float)jp) / 40.0f);
  float val = (float)(j < 20 ? hpos : wpos) * inv;
  cosT[s * 40 + j] = cosf(val);
  sinT[s * 40 + j] = sinf(val);
}

// ---------------- weight transpose+convert v2: wide reads/writes ----------------
__global__ __launch_bounds__(256) void transpose_w(
    const float* __restrict__ W, int ldW, long long wstep,
    unsigned short* __restrict__ Wt, long long tstep, int Ksrc, int Kpad) {
  __shared__ float t[32][132];
  W += (long long)blockIdx.z * wstep;
  Wt += (long long)blockIdx.z * tstep;
  int k0 = blockIdx.x << 7, n0 = blockIdx.y << 5;
#pragma unroll
  for (int i = 0; i < 4; ++i) {
    int flat = threadIdx.x + (i << 8);
    int r = flat >> 3, c4 = (flat & 7) << 2;
    float4 v = make_float4(0.f, 0.f, 0.f, 0.f);
    if (k0 + r < Ksrc) v = *(const float4*)&W[(long long)(k0 + r) * ldW + n0 + c4];
    t[c4][r] = v.x;
    t[c4 + 1][r] = v.y;
    t[c4 + 2][r] = v.z;
    t[c4 + 3][r] = v.w;
  }
  __syncthreads();
  int n = threadIdx.x >> 3, kb = (threadIdx.x & 7) << 2;
#pragma unroll
  for (int j = 0; j < 4; ++j) {
    int k = kb + (j << 5);
    if (k0 + k < Kpad) {
      short4v o;
      o[0] = (short)f2bf(t[n][k]);
      o[1] = (short)f2bf(t[n][k + 1]);
      o[2] = (short)f2bf(t[n][k + 2]);
      o[3] = (short)f2bf(t[n][k + 3]);
      *(short4v*)&Wt[(long long)(n0 + n) * Kpad + k0 + k] = o;
    }
  }
}

// ---------------- x convert ----------------
__global__ __launch_bounds__(256) void convert_x(const float* __restrict__ x,
                                                 unsigned short* __restrict__ xb) {
  int idx = blockIdx.x * 256 + threadIdx.x;
  if (idx >= SEQ * PATCH_PAD) return;
  int j = idx % PATCH_PAD, s = idx / PATCH_PAD;
  xb[idx] = (j < PATCH_DIMS) ? f2bf(x[(long long)s * PATCH_DIMS + j]) : 0;
}

// ---------------- split-K bf16 MFMA GEMM (128x128), XCD-swizzled ----------------
// mode 0: bf16 partial at part[bz][M][N]; mode 3: (s==1) bf16 out = swish(v+bias)
__global__ __launch_bounds__(256) void gemm_sk(
    const unsigned short* __restrict__ A, int lda,
    const unsigned short* __restrict__ Bt, int ldb,
    void* __restrict__ outp, const float* __restrict__ bias,
    int M, int N, int K, int chunk, int mode) {
  __shared__ short As[128 * 32];
  __shared__ short Bs[128 * 32];
  int nbx = gridDim.x, nby = gridDim.y, nbz = gridDim.z;
  int orig = blockIdx.x + nbx * (blockIdx.y + nby * blockIdx.z);
  int nwg = nbx * nby * nbz;
  int q = nwg >> 3, r = nwg & 7;
  int xcd = orig & 7, pos = orig >> 3;
  int lid = (xcd < r ? xcd * (q + 1) : r * (q + 1) + (xcd - r) * q) + pos;
  int bx = lid % nbx;
  int tt = lid / nbx;
  int by = tt % nby;
  int bz = tt / nby;

  int bm = by << 7, bn = bx << 7;
  int k0 = bz * chunk;
  int kend = min(K, k0 + chunk);
  int tid = threadIdx.x;
  int lane = tid & 63, wid = tid >> 6;
  int wr = wid >> 1, wc = wid & 1;
  f32x4 acc[4][4] = {};

  int arow = (wid << 4) + (lane >> 2);
  int kblk = (lane & 3) << 3;
  const unsigned short* ga = A + (long long)(bm + arow) * lda + k0 + kblk;
  const unsigned short* gb = Bt + (long long)(bn + arow) * ldb + k0 + kblk;
  short* la = &As[arow * 32 + kblk];
  short* lb = &Bs[arow * 32 + kblk];
  long long stepA = 64LL * lda, stepB = 64LL * ldb;

  int l15 = lane & 15, kb8 = (lane >> 4) << 3;
  int rowA = (wr << 6) + l15;
  int rowB = (wc << 6) + l15;

  for (int k = k0; k < kend; k += 32) {
    __syncthreads();
    GLOAD16(ga, la);
    GLOAD16(ga + stepA, la + 64 * 32);
    GLOAD16(gb, lb);
    GLOAD16(gb + stepB, lb + 64 * 32);
    ga += 32;
    gb += 32;
    __syncthreads();
    short8 af[4], bfr[4];
#pragma unroll
    for (int m = 0; m < 4; ++m)
      af[m] = *(const short8*)&As[(rowA + (m << 4)) * 32 + kb8];
#pragma unroll
    for (int n = 0; n < 4; ++n)
      bfr[n] = *(const short8*)&Bs[(rowB + (n << 4)) * 32 + kb8];
#pragma unroll
    for (int m = 0; m < 4; ++m)
#pragma unroll
      for (int n = 0; n < 4; ++n)
        acc[m][n] = __builtin_amdgcn_mfma_f32_16x16x32_bf16(af[m], bfr[n], acc[m][n], 0, 0, 0);
  }

  int lg = lane >> 4;
  unsigned short* Cp = (unsigned short*)outp + (long long)bz * M * N;
  unsigned short* Cb = (unsigned short*)outp;
#pragma unroll
  for (int m = 0; m < 4; ++m) {
    int row0 = bm + (wr << 6) + (m << 4) + (lg << 2);
#pragma unroll
    for (int n = 0; n < 4; ++n) {
      int col = bn + (wc << 6) + (n << 4) + l15;
      float bval = (mode == 3) ? bias[col] : 0.f;
#pragma unroll
      for (int r2 = 0; r2 < 4; ++r2) {
        int row = row0 + r2;
        float v = acc[m][n][r2];
        if (mode == 0) {
          Cp[(long long)row * N + col] = f2bf(v);
        } else {
          v += bval;
          Cb[(long long)row * N + col] = f2bf(v / (1.0f + __expf(-1.702f * v)));
        }
      }
    }
  }
}

// ---------------- split-K reduce (bf16 partials) + epilogue ----------------
// mode: 0 f32 (+bias if non-null) | 3 bf16 swish+bias | 4 bf16 gelu+bias
__global__ __launch_bounds__(256) void reduce_sk(
    const unsigned short* __restrict__ P, long long MN, int nsplit,
    const float* __restrict__ bias,
    void* __restrict__ out, int N, int ldout, int colbase, int mode) {
  long long i = ((long long)blockIdx.x * 256 + threadIdx.x) * 4;
  if (i >= MN) return;
  float v[4] = {0.f, 0.f, 0.f, 0.f};
  for (int s = 0; s < nsplit; ++s) {
    short4v p = *(const short4v*)&P[s * MN + i];
#pragma unroll
    for (int j = 0; j < 4; ++j) v[j] += bf2f((unsigned short)p[j]);
  }
  int row = (int)(i / N), col = (int)(i % N);
  if (bias) {
    float4 bv = *(const float4*)&bias[col];
    v[0] += bv.x; v[1] += bv.y; v[2] += bv.z; v[3] += bv.w;
  }
  long long oi = (long long)row * ldout + colbase + col;
  if (mode == 0) {
    *(float4*)&((float*)out)[oi] = make_float4(v[0], v[1], v[2], v[3]);
  } else if (mode == 3) {
    short4v o;
#pragma unroll
    for (int j = 0; j < 4; ++j)
      o[j] = (short)f2bf(v[j] / (1.0f + __expf(-1.702f * v[j])));
    *(short4v*)&((unsigned short*)out)[oi] = o;
  } else {
    short4v o;
#pragma unroll
    for (int j = 0; j < 4; ++j)
      o[j] = (short)f2bf(0.5f * v[j] * (1.0f + tanhf(0.79788456080286535588f *
                                                     (v[j] + 0.044715f * v[j] * v[j] * v[j]))));
    *(short4v*)&((unsigned short*)out)[oi] = o;
  }
}

// ---------------- split-K reduce (bf16) + residual + LayerNorm fusion ----------------
__global__ __launch_bounds__(320) void reduce_ln(
    const unsigned short* __restrict__ P, int nsplit,
    const float* __restrict__ bias, const float* __restrict__ res,
    const float* __restrict__ g, const float* __restrict__ b,
    float* __restrict__ hout, unsigned short* __restrict__ yout) {
  int r = blockIdx.x, tid = threadIdx.x;
  int c4 = tid << 2;
  const long long MN = (long long)SEQ * EMBED;
  const unsigned short* prow = P + (long long)r * EMBED;
  __shared__ float r0[5], r1[5];
  float4 v = make_float4(0.f, 0.f, 0.f, 0.f);
  if (bias) v = *(const float4*)&bias[c4];
  for (int z = 0; z < nsplit; ++z) {
    short4v p = *(const short4v*)&prow[(long long)z * MN + c4];
    v.x += bf2f((unsigned short)p[0]);
    v.y += bf2f((unsigned short)p[1]);
    v.z += bf2f((unsigned short)p[2]);
    v.w += bf2f((unsigned short)p[3]);
  }
  if (res) {
    float4 rv = *(const float4*)&res[(long long)r * EMBED + c4];
    v.x += rv.x; v.y += rv.y; v.z += rv.z; v.w += rv.w;
  }
  float s = v.x + v.y + v.z + v.w;
  float sq = v.x * v.x + v.y * v.y + v.z * v.z + v.w * v.w;
  s = waveReduceSum(s);
  sq = waveReduceSum(sq);
  int lane = tid & 63, wid = tid >> 6;
  if (!lane) { r0[wid] = s; r1[wid] = sq; }
  __syncthreads();
  s = r0[0] + r0[1] + r0[2] + r0[3] + r0[4];
  sq = r1[0] + r1[1] + r1[2] + r1[3] + r1[4];
  float mean = s * (1.0f / EMBED);
  float var = sq * (1.0f / EMBED) - mean * mean;
  float rstd = rsqrtf(var + 1e-6f);
  *(float4*)&hout[(long long)r * EMBED + c4] = v;
  float4 gv = *(const float4*)&g[c4];
  float4 bv = *(const float4*)&b[c4];
  short4v o;
  o[0] = (short)f2bf((v.x - mean) * rstd * gv.x + bv.x);
  o[1] = (short)f2bf((v.y - mean) * rstd * gv.y + bv.y);
  o[2] = (short)f2bf((v.z - mean) * rstd * gv.z + bv.z);
  o[3] = (short)f2bf((v.w - mean) * rstd * gv.w + bv.w);
  *(short4v*)&yout[(long long)r * EMBED + c4] = o;
}

// ---------------- fused qkv reduce: q/k rope (blocks 0..1023) + V pack (blocks 1024..1279) ----------------
__global__ __launch_bounds__(256) void reduce_qkvv(
    const unsigned short* __restrict__ P, int nsplit,
    const float* __restrict__ bias,
    const float* __restrict__ cosT, const float* __restrict__ sinT,
    unsigned short* __restrict__ qb, unsigned short* __restrict__ kb,
    unsigned short* __restrict__ vb, float qscale) {
  __shared__ unsigned short t[80][72];
  int b = blockIdx.x, tid = threadIdx.x;
  const long long MN = (long long)SEQ * QKV3;
  if (b < SEQ) {
    int s = b;
    const unsigned short* prow = P + (long long)s * QKV3;
    for (int idx = tid; idx < 640; idx += 256) {
      int hh = idx / 40, j = idx % 40;
      int cq = hh * 80 + j;
      float q0 = bias[cq], q1 = bias[cq + 40];
      float k0 = bias[1280 + cq], k1 = bias[1280 + cq + 40];
      for (int z = 0; z < nsplit; ++z) {
        const unsigned short* p = prow + (long long)z * MN;
        q0 += bf2f(p[cq]); q1 += bf2f(p[cq + 40]);
        k0 += bf2f(p[1280 + cq]); k1 += bf2f(p[1280 + cq + 40]);
      }
      float cs = cosT[s * 40 + j], sn = sinT[s * 40 + j];
      size_t o = ((size_t)hh * SEQ + s) * HDP;
      qb[o + j] = f2bf((q0 * cs - q1 * sn) * qscale);
      qb[o + j + 40] = f2bf((q1 * cs + q0 * sn) * qscale);
      kb[o + j] = f2bf(k0 * cs - k1 * sn);
      kb[o + j + 40] = f2bf(k1 * cs + k0 * sn);
    }
    {
      int hh = tid >> 4, p = 80 + (tid & 15);
      size_t o = ((size_t)hh * SEQ + s) * HDP + p;
      qb[o] = 0;
      kb[o] = 0;
    }
  } else {
    int bb = b - SEQ;
    int hh = bb >> 4, s0 = (bb & 15) << 6;
    int s = tid >> 2, c0 = (tid & 3) * 20;
    const unsigned short* prow =
        P + (long long)(s0 + s) * QKV3 + 2560 + hh * 80 + c0;
#pragma unroll
    for (int j = 0; j < 20; ++j) {
      float v = bias[2560 + hh * 80 + c0 + j];
      for (int z = 0; z < nsplit; ++z) v += bf2f(prow[(long long)z * MN + j]);
      t[c0 + j][s] = f2bf(v);
    }
    __syncthreads();
    unsigned short* dst = vb + (size_t)hh * 80 * SEQ + s0;
#pragma unroll
    for (int i = 0; i < 3; ++i) {
      int c = tid + (i << 8);
      if (c < 640) {
        int dr = c >> 3, col = (c & 7) << 3;
        *(short8*)&dst[(size_t)dr * SEQ + col] = *(const short8*)&t[dr][col];
      }
    }
  }
}

// ---------------- fused flash attention, KV-split x4, bf16 Opart ----------------
__global__ __launch_bounds__(256) void flash_attn_split(
    const unsigned short* __restrict__ qb,
    const unsigned short* __restrict__ kb,
    const unsigned short* __restrict__ vb,
    unsigned short* __restrict__ Opart, // [KVSPLIT][SEQ][EMBED] bf16
    float* __restrict__ mlbuf) {        // [z*2+{0:m,1:l}][HEADS][SEQ]
  __shared__ short Ks[64 * 104];
  __shared__ short Vs[80 * 72];
  __shared__ short Ps[4 * 16 * 72];
  int h = blockIdx.y, q0 = blockIdx.x << 6, z = blockIdx.z;
  int tid = threadIdx.x, lane = tid & 63, wid = tid >> 6;
  int l15 = lane & 15, lg = lane >> 4;
  int kb8 = lg << 3;

  short8 qf[3];
  {
    const unsigned short* qrow = qb + ((size_t)h * SEQ + q0 + (wid << 4) + l15) * HDP;
#pragma unroll
    for (int dc = 0; dc < 3; ++dc) qf[dc] = *(const short8*)&qrow[dc * 32 + kb8];
  }

  f32x4 o_acc[5] = {};
  float m_run = -1e30f, l_run = 0.f;
  short* myP = &Ps[(wid * 16 + l15) * 72];

  const int TPS = 16 / KVSPLIT;
  for (int t = z * TPS; t < z * TPS + TPS; ++t) {
    int kv0 = t << 6;
    __syncthreads();
    {
      const unsigned short* gk = kb + ((size_t)h * SEQ + kv0) * HDP;
#pragma unroll
      for (int i = 0; i < 3; ++i) {
        int c = tid + (i << 8);
        int row = c / 12, col = (c % 12) << 3;
        *(short8*)&Ks[row * 104 + col] = *(const short8*)&gk[row * HDP + col];
      }
      const unsigned short* gv = vb + (size_t)h * 80 * SEQ + kv0;
#pragma unroll
      for (int i = 0; i < 3; ++i) {
        int c = tid + (i << 8);
        if (c < 640) {
          int row = c >> 3, col = (c & 7) << 3;
          *(short8*)&Vs[row * 72 + col] = *(const short8*)&gv[(size_t)row * SEQ + col];
        }
      }
    }
    __syncthreads();

    f32x4 s[4] = {};
#pragma unroll
    for (int ks = 0; ks < 4; ++ks) {
#pragma unroll
      for (int dc = 0; dc < 3; ++dc) {
        short8 kf = *(const short8*)&Ks[(ks * 16 + l15) * 104 + dc * 32 + kb8];
        s[ks] = __builtin_amdgcn_mfma_f32_16x16x32_bf16(kf, qf[dc], s[ks], 0, 0, 0);
      }
    }

    float mloc = -1e30f;
#pragma unroll
    for (int ks = 0; ks < 4; ++ks)
#pragma unroll
      for (int r = 0; r < 4; ++r) mloc = fmaxf(mloc, s[ks][r]);
    mloc = fmaxf(mloc, __shfl_xor(mloc, 16));
    mloc = fmaxf(mloc, __shfl_xor(mloc, 32));
    float m_new = fmaxf(m_run, mloc);
    float alpha = __expf(m_run - m_new);
    float psum = 0.f;
#pragma unroll
    for (int ks = 0; ks < 4; ++ks) {
      short4v pk;
#pragma unroll
      for (int r = 0; r < 4; ++r) {
        float p = __expf(s[ks][r] - m_new);
        psum += p;
        pk[r] = (short)f2bf(p);
      }
      *(short4v*)&myP[ks * 16 + (lg << 2)] = pk;
    }
    psum += __shfl_xor(psum, 16);
    psum += __shfl_xor(psum, 32);
    l_run = l_run * alpha + psum;
    m_run = m_new;
#pragma unroll
    for (int dt = 0; dt < 5; ++dt)
#pragma unroll
      for (int r = 0; r < 4; ++r) o_acc[dt][r] *= alpha;

#pragma unroll
    for (int dt = 0; dt < 5; ++dt) {
#pragma unroll
      for (int kc = 0; kc < 2; ++kc) {
        short8 vf = *(const short8*)&Vs[(dt * 16 + l15) * 72 + kc * 32 + kb8];
        short8 pf = *(const short8*)&myP[kc * 32 + kb8];
        o_acc[dt] = __builtin_amdgcn_mfma_f32_16x16x32_bf16(vf, pf, o_acc[dt], 0, 0, 0);
      }
    }
  }

  int row = q0 + (wid << 4) + l15;
  unsigned short* orow = Opart + ((size_t)z * SEQ + row) * EMBED + h * HD;
#pragma unroll
  for (int dt = 0; dt < 5; ++dt) {
    short4v ov;
#pragma unroll
    for (int r = 0; r < 4; ++r) ov[r] = (short)f2bf(o_acc[dt][r]);
    *(short4v*)&orow[dt * 16 + (lg << 2)] = ov;
  }
  if (lg == 0) {
    mlbuf[((size_t)(z * 2 + 0) * HEADS + h) * SEQ + row] = m_run;
    mlbuf[((size_t)(z * 2 + 1) * HEADS + h) * SEQ + row] = l_run;
  }
}

// ---------------- combine the KV splits (bf16 Opart) ----------------
__global__ __launch_bounds__(320) void flash_combine(
    const unsigned short* __restrict__ Opart, const float* __restrict__ mlbuf,
    unsigned short* __restrict__ ob) {
  int s = blockIdx.x, tid = threadIdx.x;
  __shared__ float ws[KVSPLIT][16], ils[16];
  if (tid < 16) {
    float m = -1e30f;
    float mv[KVSPLIT], lv[KVSPLIT];
#pragma unroll
    for (int z = 0; z < KVSPLIT; ++z) {
      mv[z] = mlbuf[((size_t)(z * 2 + 0) * HEADS + tid) * SEQ + s];
      lv[z] = mlbuf[((size_t)(z * 2 + 1) * HEADS + tid) * SEQ + s];
      m = fmaxf(m, mv[z]);
    }
    float denom = 0.f;
#pragma unroll
    for (int z = 0; z < KVSPLIT; ++z) {
      float w = __expf(mv[z] - m);
      ws[z][tid] = w;
      denom += w * lv[z];
    }
    ils[tid] = 1.0f / denom;
  }
  __syncthreads();
  int c = tid << 2, hh = c / 80;
  float a0 = 0.f, a1 = 0.f, a2 = 0.f, a3 = 0.f;
#pragma unroll
  for (int z = 0; z < KVSPLIT; ++z) {
    short4v o = *(const short4v*)&Opart[((size_t)z * SEQ + s) * EMBED + c];
    float w = ws[z][hh];
    a0 += bf2f((unsigned short)o[0]) * w;
    a1 += bf2f((unsigned short)o[1]) * w;
    a2 += bf2f((unsigned short)o[2]) * w;
    a3 += bf2f((unsigned short)o[3]) * w;
  }
  float il = ils[hh];
  short4v o;
  o[0] = (short)f2bf(a0 * il);
  o[1] = (short)f2bf(a1 * il);
  o[2] = (short)f2bf(a2 * il);
  o[3] = (short)f2bf(a3 * il);
  *(short4v*)&ob[(size_t)s * EMBED + c] = o;
}

extern "C" void kernel_launch(void* const* d_in, const int* in_sizes, int n_in,
                              void* d_out, int out_size, void* d_ws, size_t ws_size,
                              hipStream_t stream) {
  const float* x = (const float*)d_in[0];
  const float* patch_w = (const float*)d_in[1];
  const float* ln1_g = (const float*)d_in[2];
  const float* ln1_b = (const float*)d_in[3];
  const float* qkv_w = (const float*)d_in[4];
  const float* qkv_b = (const float*)d_in[5];
  const float* proj_w = (const float*)d_in[6];
  const float* proj_b = (const float*)d_in[7];
  const float* ln2_g = (const float*)d_in[8];
  const float* ln2_b = (const float*)d_in[9];
  const float* fc1_w = (const float*)d_in[10];
  const float* fc1_b = (const float*)d_in[11];
  const float* fc2_w = (const float*)d_in[12];
  const float* fc2_b = (const float*)d_in[13];
  const float* mln_g = (const float*)d_in[14];
  const float* mln_b = (const float*)d_in[15];
  const float* mfc1_w = (const float*)d_in[16];
  const float* mfc1_b = (const float*)d_in[17];
  const float* mfc2_w = (const float*)d_in[18];
  const float* mfc2_b = (const float*)d_in[19];
  const int* grid_h = (const int*)d_in[21];
  const int* grid_w = (const int*)d_in[22];

  char* wsp = (char*)d_ws;
  char* ws0 = wsp;
  float* h = (float*)wsp;                       wsp += (size_t)SEQ * EMBED * 4;
  float* cosT = (float*)wsp;                    wsp += (size_t)SEQ * 40 * 4;
  float* sinT = (float*)wsp;                    wsp += (size_t)SEQ * 40 * 4;
  unsigned short* y = (unsigned short*)wsp;     wsp += (size_t)SEQ * EMBED * 2;
  unsigned short* ob = (unsigned short*)wsp;    wsp += (size_t)SEQ * EMBED * 2;
  unsigned short* m1b = (unsigned short*)wsp;   wsp += (size_t)MSEQ * MDIM * 2;
  unsigned short* qb = (unsigned short*)wsp;    wsp += (size_t)HEADS * SEQ * HDP * 2;
  unsigned short* kb = (unsigned short*)wsp;    wsp += (size_t)HEADS * SEQ * HDP * 2;
  unsigned short* vb = (unsigned short*)wsp;    wsp += (size_t)HEADS * HD * SEQ * 2;
  unsigned short* Opart = (unsigned short*)wsp; wsp += (size_t)KVSPLIT * SEQ * EMBED * 2;
  float* mlbuf = (float*)wsp;                   wsp += (size_t)2 * KVSPLIT * HEADS * SEQ * 4;
  unsigned short* u = (unsigned short*)wsp;     wsp += (size_t)SEQ * MLP_DIM * 2;
  unsigned short* xb = (unsigned short*)wsp;    wsp += (size_t)SEQ * PATCH_PAD * 2;
  unsigned short* wt = (unsigned short*)wsp;    wsp += (size_t)(MDIM / 2) * MDIM * 2;
  size_t fixed = (size_t)(wsp - ws0);

  const size_t E_QKV = (size_t)QKV3 * EMBED;
  const size_t E_PROJ = (size_t)EMBED * EMBED;
  const size_t E_FC1 = (size_t)MLP_DIM * EMBED;
  const size_t E_FC2 = (size_t)EMBED * MLP_DIM;
  const size_t E_PATCH = (size_t)EMBED * PATCH_PAD;
  const size_t E_M1 = (size_t)MDIM * MDIM;
  const size_t E_M2 = (size_t)HIDDEN * MDIM;
  size_t wregElems = DEPTH * (E_QKV + E_PROJ + E_FC1 + E_FC2) + E_PATCH + E_M1 + E_M2;
  size_t wregBytes = wregElems * 2;
  bool full = ws_size >= fixed + wregBytes + (size_t)90 * 1024 * 1024;

  unsigned short* wreg = (unsigned short*)wsp;
  unsigned short* Wq = wreg;
  unsigned short* Wp = Wq + DEPTH * E_QKV;
  unsigned short* Wf1 = Wp + DEPTH * E_PROJ;
  unsigned short* Wf2 = Wf1 + DEPTH * E_FC1;
  unsigned short* Wpa = Wf2 + DEPTH * E_FC2;
  unsigned short* Wm1 = Wpa + E_PATCH;
  unsigned short* Wm2 = Wm1 + E_M1;

  unsigned short* part =
      full ? (unsigned short*)(wsp + wregBytes) : (unsigned short*)wsp;
  size_t avail = ws_size - fixed - (full ? wregBytes : 0);

  auto splits_for = [&](long long MN, int want) {
    size_t one = (size_t)MN * 2;
    if (avail < one) return 1;
    long long cap = (long long)(avail / one);
    return (int)(want < cap ? want : cap);
  };
  auto chunk_for = [](int K, int s) { return ((K + s * 32 - 1) / (s * 32)) * 32; };

  const float scale = 1.0f / sqrtf(80.0f);
  dim3 blk(256);

  rope_tables_kernel<<<SEQ, 64, 0, stream>>>(grid_h, grid_w, cosT, sinT);
  convert_x<<<(SEQ * PATCH_PAD + 255) / 256, blk, 0, stream>>>(x, xb);

  if (full) {
    transpose_w<<<dim3((PATCH_PAD + 127) / 128, EMBED / 32, 1), blk, 0, stream>>>(
        patch_w, EMBED, 0, Wpa, 0, PATCH_DIMS, PATCH_PAD);
    transpose_w<<<dim3(EMBED / 128, QKV3 / 32, DEPTH), blk, 0, stream>>>(
        qkv_w, QKV3, (long long)EMBED * QKV3, Wq, (long long)E_QKV, EMBED, EMBED);
    transpose_w<<<dim3(EMBED / 128, EMBED / 32, DEPTH), blk, 0, stream>>>(
        proj_w, EMBED, (long long)EMBED * EMBED, Wp, (long long)E_PROJ, EMBED, EMBED);
    transpose_w<<<dim3(EMBED / 128, MLP_DIM / 32, DEPTH), blk, 0, stream>>>(
        fc1_w, MLP_DIM, (long long)EMBED * MLP_DIM, Wf1, (long long)E_FC1, EMBED, EMBED);
    transpose_w<<<dim3(MLP_DIM / 128, EMBED / 32, DEPTH), blk, 0, stream>>>(
        fc2_w, EMBED, (long long)MLP_DIM * EMBED, Wf2, (long long)E_FC2, MLP_DIM, MLP_DIM);
    transpose_w<<<dim3(MDIM / 128, MDIM / 32, 1), blk, 0, stream>>>(
        mfc1_w, MDIM, 0, Wm1, 0, MDIM, MDIM);
    transpose_w<<<dim3(MDIM / 128, HIDDEN / 32, 1), blk, 0, stream>>>(
        mfc2_w, HIDDEN, 0, Wm2, 0, MDIM, MDIM);
  }

  // ---- patch embed + LN1(layer0): split 6 (480 blocks) ----
  {
    const unsigned short* W = Wpa;
    if (!full) {
      transpose_w<<<dim3((PATCH_PAD + 127) / 128, EMBED / 32, 1), blk, 0, stream>>>(
          patch_w, EMBED, 0, wt, 0, PATCH_DIMS, PATCH_PAD);
      W = wt;
    }
    long long MN = (long long)SEQ * EMBED;
    int s = splits_for(MN, 6), ch = chunk_for(PATCH_PAD, s);
    gemm_sk<<<dim3(EMBED / 128, SEQ / 128, s), blk, 0, stream>>>(
        xb, PATCH_PAD, W, PATCH_PAD, part, nullptr, SEQ, EMBED, PATCH_PAD, ch, 0);
    reduce_ln<<<SEQ, 320, 0, stream>>>(part, s, nullptr, nullptr, ln1_g, ln1_b, h, y);
  }

  for (int l = 0; l < DEPTH; ++l) {
    // qkv: split 2 (480 blocks)
    int sq;
    {
      const unsigned short* W = Wq + (size_t)l * E_QKV;
      if (!full) {
        transpose_w<<<dim3(EMBED / 128, QKV3 / 32, 1), blk, 0, stream>>>(
            qkv_w + (long long)l * EMBED * QKV3, QKV3, 0, wt, 0, EMBED, EMBED);
        W = wt;
      }
      long long MN = (long long)SEQ * QKV3;
      sq = splits_for(MN, 2);
      int ch = chunk_for(EMBED, sq);
      gemm_sk<<<dim3(QKV3 / 128, SEQ / 128, sq), blk, 0, stream>>>(
          y, EMBED, W, EMBED, part, nullptr, SEQ, QKV3, EMBED, ch, 0);
      reduce_qkvv<<<SEQ + 16 * HEADS, blk, 0, stream>>>(
          part, sq, qkv_b + l * QKV3, cosT, sinT, qb, kb, vb, scale);
    }
    flash_attn_split<<<dim3(SEQ / 64, HEADS, KVSPLIT), blk, 0, stream>>>(
        qb, kb, vb, Opart, mlbuf);
    flash_combine<<<SEQ, 320, 0, stream>>>(Opart, mlbuf, ob);
    // proj: split 6 (480 blocks), reduce_ln (+res +LN2)
    {
      const unsigned short* W = Wp + (size_t)l * E_PROJ;
      if (!full) {
        transpose_w<<<dim3(EMBED / 128, EMBED / 32, 1), blk, 0, stream>>>(
            proj_w + (long long)l * EMBED * EMBED, EMBED, 0, wt, 0, EMBED, EMBED);
        W = wt;
      }
      long long MN = (long long)SEQ * EMBED;
      int s = splits_for(MN, 6), ch = chunk_for(EMBED, s);
      gemm_sk<<<dim3(EMBED / 128, SEQ / 128, s), blk, 0, stream>>>(
          ob, EMBED, W, EMBED, part, nullptr, SEQ, EMBED, EMBED, ch, 0);
      reduce_ln<<<SEQ, 320, 0, stream>>>(part, s, proj_b + l * EMBED, h,
                                         ln2_g + l * EMBED, ln2_b + l * EMBED, h, y);
    }
    // fc1: split 2 (640 blocks) + swish reduce -> u bf16
    {
      const unsigned short* W = Wf1 + (size_t)l * E_FC1;
      if (!full) {
        transpose_w<<<dim3(EMBED / 128, MLP_DIM / 32, 1), blk, 0, stream>>>(
            fc1_w + (long long)l * EMBED * MLP_DIM, MLP_DIM, 0, wt, 0, EMBED, EMBED);
        W = wt;
      }
      long long MN = (long long)SEQ * MLP_DIM;
      int s = splits_for(MN, 2), ch = chunk_for(EMBED, s);
      gemm_sk<<<dim3(MLP_DIM / 128, SEQ / 128, s), blk, 0, stream>>>(
          y, EMBED, W, EMBED, part, nullptr, SEQ, MLP_DIM, EMBED, ch, 0);
      reduce_sk<<<(MN / 4 + 255) / 256, blk, 0, stream>>>(
          part, MN, s, fc1_b + l * MLP_DIM, u, MLP_DIM, MLP_DIM, 0, 3);
    }
    // fc2: split 8 (640 blocks), reduce_ln (+res +next-LN)
    {
      const unsigned short* W = Wf2 + (size_t)l * E_FC2;
      if (!full) {
        transpose_w<<<dim3(MLP_DIM / 128, EMBED / 32, 1), blk, 0, stream>>>(
            fc2_w + (long long)l * MLP_DIM * EMBED, EMBED, 0, wt, 0, MLP_DIM, MLP_DIM);
        W = wt;
      }
      long long MN = (long long)SEQ * EMBED;
      int s = splits_for(MN, 8), ch = chunk_for(MLP_DIM, s);
      gemm_sk<<<dim3(EMBED / 128, SEQ / 128, s), blk, 0, stream>>>(
          u, MLP_DIM, W, MLP_DIM, part, nullptr, SEQ, EMBED, MLP_DIM, ch, 0);
      const float* ng = (l < DEPTH - 1) ? ln1_g + (l + 1) * EMBED : mln_g;
      const float* nb = (l < DEPTH - 1) ? ln1_b + (l + 1) * EMBED : mln_b;
      reduce_ln<<<SEQ, 320, 0, stream>>>(part, s, fc2_b + l * EMBED, h, ng, nb, h, y);
    }
  }

  // ---- merger (split 8, chunk 672 like fc2) ----
  if (full) {
    {
      long long MN = (long long)MSEQ * MDIM;
      int s = splits_for(MN, 8), ch = chunk_for(MDIM, s);
      gemm_sk<<<dim3(MDIM / 128, MSEQ / 128, s), blk, 0, stream>>>(
          y, MDIM, Wm1, MDIM, part, nullptr, MSEQ, MDIM, MDIM, ch, 0);
      reduce_sk<<<(MN / 4 + 255) / 256, blk, 0, stream>>>(
          part, MN, s, mfc1_b, m1b, MDIM, MDIM, 0, 4);
    }
    {
      long long MN = (long long)MSEQ * HIDDEN;
      int s = splits_for(MN, 8), ch = chunk_for(MDIM, s);
      gemm_sk<<<dim3(HIDDEN / 128, MSEQ / 128, s), blk, 0, stream>>>(
          m1b, MDIM, Wm2, MDIM, part, nullptr, MSEQ, HIDDEN, MDIM, ch, 0);
      reduce_sk<<<(MN / 4 + 255) / 256, blk, 0, stream>>>(
          part, MN, s, mfc2_b, (float*)d_out, HIDDEN, HIDDEN, 0, 0);
    }
  } else {
    for (int hh = 0; hh < 2; ++hh) {
      transpose_w<<<dim3(MDIM / 128, 2560 / 32, 1), blk, 0, stream>>>(
          mfc1_w + hh * 2560, MDIM, 0, wt, 0, MDIM, MDIM);
      long long MN = (long long)MSEQ * 2560;
      int s = splits_for(MN, 8), ch = chunk_for(MDIM, s);
      gemm_sk<<<dim3(2560 / 128, MSEQ / 128, s), blk, 0, stream>>>(
          y, MDIM, wt, MDIM, part, nullptr, MSEQ, 2560, MDIM, ch, 0);
      reduce_sk<<<(MN / 4 + 255) / 256, blk, 0, stream>>>(
          part, MN, s, mfc1_b + hh * 2560, m1b, 2560, MDIM, hh * 2560, 4);
    }
    for (int hh = 0; hh < 2; ++hh) {
      transpose_w<<<dim3(MDIM / 128, 1792 / 32, 1), blk, 0, stream>>>(
          mfc2_w + hh * 1792, HIDDEN, 0, wt, 0, MDIM, MDIM);
      long long MN = (long long)MSEQ * 1792;
      int s = splits_for(MN, 8), ch = chunk_for(MDIM, s);
      gemm_sk<<<dim3(1792 / 128, MSEQ / 128, s), blk, 0, stream>>>(
          m1b, MDIM, wt, MDIM, part, nullptr, MSEQ, 1792, MDIM, ch, 0);
      reduce_sk<<<(MN / 4 + 255) / 256, blk, 0, stream>>>(
          part, MN, s, mfc2_b + hh * 1792, (float*)d_out, 1792, HIDDEN, hh * 1792, 0);
    }
  }
}